// Round 2
// baseline (2700.300 us; speedup 1.0000x reference)
//
#include <hip/hip_runtime.h>
#include <hip/hip_bf16.h>

#define DD 32
constexpr int N_ = 200000;
constexpr int E_ = 3200000;
constexpr int B_ = 512;

// ---------------- workspace layout (float offsets) ----------------
constexpr int OFF_EMB=0, OFF_W0=3232, OFF_B0=4256, OFF_WM=4288, OFF_WIHG=5312,
  OFF_WHHG=8384, OFF_BIHG=11456, OFF_BHHG=11552, OFF_WIH0=11648, OFF_WHH0=19840,
  OFF_BIH0=23936, OFF_BHH0=24064, OFF_WIH12=24192, OFF_WHH12=32384, OFF_BIH12=40576,
  OFF_BHH12=40832, OFF_WR1=41088, OFF_BR1=43136, OFF_WR2=43168, OFF_BR2=44192,
  OFF_WMT=44224, OFF_W0T=45248;
constexpr int OFF_QSTAR=46272;              // B*64 = 32768
constexpr int OFF_HS=79040;                 // 3*B*32 = 49152
constexpr int OFF_CS=128192;                // 49152
constexpr int OFF_OUT=177344;               // N*32 = 6.4M
constexpr long OFF_AGG=6577344L;            // N*32
constexpr long OFF_EV=12977344L;            // N
constexpr long FLOAT_END=13177344L;
constexpr size_t INT_BASE = (size_t)FLOAT_END*4;   // byte offset, 256B aligned
// int offsets (in ints, from INT_BASE)
constexpr int I_DEG=0, I_GCNT=200000, I_NOFF=200512, I_CURSOR=400512, I_GOFF=600512,
  I_BSUM=601088, I_BOFF=601344, I_CSR=601600;      // csr: E ints
constexpr int I_FLAG=3801600;

__device__ __forceinline__ float bf2f(unsigned short u){ return __uint_as_float(((unsigned)u)<<16); }
__device__ __forceinline__ float sigm(float x){ return 1.0f/(1.0f+__expf(-x)); }
__device__ __forceinline__ float tanhfast(float x){ return 1.0f - 2.0f/(__expf(2.0f*x)+1.0f); }

// ---------------- input-dtype detection ----------------
// emb row 0 is all zeros (padding_idx=0). Bytes 64..127 of the emb buffer:
//   fp32 mode: second half of row 0 -> all zero
//   bf16 mode: row 1 (random normal) -> nonzero
__global__ void k_detect(const unsigned int* __restrict__ emb_raw, int* __restrict__ flag){
  if(threadIdx.x==0){
    unsigned v=0;
    for(int i=16;i<32;i++) v |= emb_raw[i];
    flag[0] = v ? 1 : 0;   // 1 = bf16 inputs, 0 = f32 inputs
  }
}

// ---------------- weight prep: (bf16|f32) -> fp32 (+ transposed Wm, W0) ----------------
struct PrepArgs { const void* s[22]; int off[22]; int sz[22]; };

__global__ void k_prep(PrepArgs a, float* __restrict__ W, const int* __restrict__ flag){
  int bf = flag[0];
  int seg = blockIdx.y;
  int i = blockIdx.x*256 + threadIdx.x;
  if(i >= a.sz[seg]) return;
  int sidx = (seg<20) ? i : (((i&31)<<5) | (i>>5));   // segs 20/21: 32x32 transpose
  float v = bf ? bf2f(((const unsigned short*)a.s[seg])[sidx])
               : ((const float*)a.s[seg])[sidx];
  W[a.off[seg]+i] = v;
}

// ---------------- lin0: out[n] = relu(W0 @ emb[node_type[n]] + b0) ----------------
__global__ void k_lin0(const int* __restrict__ nt, const float* __restrict__ Wall,
                       float* __restrict__ out){
  int n = blockIdx.x*blockDim.x + threadIdx.x;
  if(n >= N_) return;
  int ty = nt[n]; if((unsigned)ty >= 101u) ty = 0;
  const float* er  = Wall + OFF_EMB + ty*DD;
  const float* W0T = Wall + OFF_W0T;
  const float* b0  = Wall + OFF_B0;
  float m[DD];
  #pragma unroll
  for(int j=0;j<DD;j++) m[j]=b0[j];
  #pragma unroll 4
  for(int k=0;k<DD;k++){
    float xk = er[k];
    #pragma unroll
    for(int j=0;j<DD;j++) m[j] = __fmaf_rn(W0T[k*DD+j], xk, m[j]);
  }
  float4* o4 = (float4*)(out + (size_t)n*DD);
  #pragma unroll
  for(int q=0;q<DD/4;q++){
    float4 v; v.x=fmaxf(m[q*4+0],0.f); v.y=fmaxf(m[q*4+1],0.f);
    v.z=fmaxf(m[q*4+2],0.f); v.w=fmaxf(m[q*4+3],0.f);
    o4[q]=v;
  }
}

// ---------------- CSR build ----------------
__global__ void k_deg(const int* __restrict__ dst, int* __restrict__ deg){
  int e = blockIdx.x*blockDim.x + threadIdx.x;
  if(e < E_){ int d=dst[e]; if((unsigned)d<(unsigned)N_) atomicAdd(&deg[d], 1); }
}
__global__ void k_gcnt(const int* __restrict__ gid, int* __restrict__ gcnt){
  int n = blockIdx.x*blockDim.x + threadIdx.x;
  if(n < N_){ int g=gid[n]; if((unsigned)g<(unsigned)B_) atomicAdd(&gcnt[g], 1); }
}
__global__ void __launch_bounds__(1024) k_scanA(const int* __restrict__ deg,
                       int* __restrict__ incl, int* __restrict__ bsum){
  __shared__ int sh[1024];
  int g = blockIdx.x*1024 + threadIdx.x;
  int v = (g < N_) ? deg[g] : 0;
  sh[threadIdx.x]=v; __syncthreads();
  for(int o=1;o<1024;o<<=1){
    int a = (threadIdx.x>=o) ? sh[threadIdx.x-o] : 0;
    __syncthreads();
    sh[threadIdx.x]+=a;
    __syncthreads();
  }
  if(g < N_) incl[g]=sh[threadIdx.x];
  if(threadIdx.x==1023) bsum[blockIdx.x]=sh[1023];
}
__global__ void k_scanB(const int* __restrict__ bsum, int* __restrict__ boff){
  __shared__ int sh[256];
  int t=threadIdx.x;
  int v=(t<196)?bsum[t]:0;
  sh[t]=v; __syncthreads();
  for(int o=1;o<256;o<<=1){
    int a=(t>=o)?sh[t-o]:0; __syncthreads(); sh[t]+=a; __syncthreads();
  }
  if(t<196) boff[t]=sh[t]-v;   // exclusive
}
__global__ void __launch_bounds__(1024) k_scanC(const int* __restrict__ deg,
                       const int* __restrict__ boff, int* __restrict__ noff,
                       int* __restrict__ incl_cursor){
  int g = blockIdx.x*1024 + threadIdx.x;
  if(g >= N_) return;
  int ex = incl_cursor[g] - deg[g] + boff[g>>10];
  noff[g]=ex; incl_cursor[g]=ex;   // cursor = exclusive offset
}
__global__ void k_goff(const int* __restrict__ gcnt, int* __restrict__ goff){
  __shared__ int sh[512];
  int t=threadIdx.x;
  int v=gcnt[t]; sh[t]=v; __syncthreads();
  for(int o=1;o<512;o<<=1){
    int a=(t>=o)?sh[t-o]:0; __syncthreads(); sh[t]+=a; __syncthreads();
  }
  goff[t+1]=sh[t];
  if(t==0) goff[0]=0;
}
__global__ void k_scatter(const int* __restrict__ src, const int* __restrict__ dst,
                          int* __restrict__ cursor, int* __restrict__ csr){
  int e = blockIdx.x*blockDim.x + threadIdx.x;
  if(e >= E_) return;
  int d = dst[e]; if((unsigned)d>=(unsigned)N_) return;
  int p = atomicAdd(&cursor[d], 1);
  if((unsigned)p < (unsigned)E_) csr[p] = src[e];
}

// ---------------- aggregation: agg[n] = sum_{e: dst=n} out[src[e]] ----------------
__global__ void k_agg(const int* __restrict__ noff, const int* __restrict__ deg,
                      const int* __restrict__ csr, const float* __restrict__ out,
                      float* __restrict__ agg){
  int t = blockIdx.x*blockDim.x + threadIdx.x;
  int n = t>>5, lane = t&31;
  if(n >= N_) return;
  int s0 = noff[n], len = deg[n];
  if(len < 0) len = 0;
  float acc = 0.f;
  for(int i=0;i<len;i++){
    int s = csr[s0+i];
    if((unsigned)s < (unsigned)N_)
      acc += out[(size_t)s*DD + lane];
  }
  agg[(size_t)n*DD + lane] = acc;
}

// ---------------- node update: m = relu(Wm@agg); h' = GRU(m, h); out = h' ----------------
__global__ void k_node(const float* __restrict__ Wall, const float* __restrict__ agg,
                       float* __restrict__ out){
  int n = blockIdx.x*blockDim.x + threadIdx.x;
  if(n >= N_) return;
  const float* WmT = Wall + OFF_WMT;
  const float* Wih = Wall + OFF_WIHG;
  const float* Whh = Wall + OFF_WHHG;
  const float* bih = Wall + OFF_BIHG;
  const float* bhh = Wall + OFF_BHHG;
  float h[DD];
  const float4* hr4 = (const float4*)(out + (size_t)n*DD);
  #pragma unroll
  for(int q=0;q<DD/4;q++){ float4 v=hr4[q]; h[q*4]=v.x; h[q*4+1]=v.y; h[q*4+2]=v.z; h[q*4+3]=v.w; }
  float m[DD];
  #pragma unroll
  for(int j=0;j<DD;j++) m[j]=0.f;
  const float* ar = agg + (size_t)n*DD;
  #pragma unroll 4
  for(int k=0;k<DD;k++){
    float xk = ar[k];
    #pragma unroll
    for(int j=0;j<DD;j++) m[j] = __fmaf_rn(WmT[k*DD+j], xk, m[j]);
  }
  #pragma unroll
  for(int j=0;j<DD;j++) m[j]=fmaxf(m[j],0.f);
  float* orow = out + (size_t)n*DD;
  #pragma unroll 2
  for(int j=0;j<DD;j++){
    float gr=bih[j],      gz=bih[j+DD],      gn=bih[j+2*DD];
    float pr=bhh[j],      pz=bhh[j+DD],      pn=bhh[j+2*DD];
    #pragma unroll
    for(int k=0;k<DD;k++){
      float mk=m[k], hk=h[k];
      gr=__fmaf_rn(Wih[j*DD+k],        mk, gr);
      gz=__fmaf_rn(Wih[(j+DD)*DD+k],   mk, gz);
      gn=__fmaf_rn(Wih[(j+2*DD)*DD+k], mk, gn);
      pr=__fmaf_rn(Whh[j*DD+k],        hk, pr);
      pz=__fmaf_rn(Whh[(j+DD)*DD+k],   hk, pz);
      pn=__fmaf_rn(Whh[(j+2*DD)*DD+k], hk, pn);
    }
    float r=sigm(gr+pr), z=sigm(gz+pz), nn=tanhfast(gn + r*pn);
    orow[j] = (1.f-z)*nn + z*h[j];
  }
}

// ---------------- Set2Set: 3-layer LSTM (rows independent) ----------------
__global__ void k_lstm(const float* __restrict__ Wall, float* __restrict__ qstar,
                       float* __restrict__ hs, float* __restrict__ cs){
  int t=threadIdx.x; int g8=t>>5; int lane=t&31;
  int row = blockIdx.x*8 + g8;
  __shared__ float xbuf[8][64];
  __shared__ float hbuf[8][32];
  xbuf[g8][lane]    = qstar[row*64+lane];
  xbuf[g8][lane+32] = qstar[row*64+32+lane];
  int xdim=64;
  const float* Wih=Wall+OFF_WIH0; const float* Whh=Wall+OFF_WHH0;
  const float* bih=Wall+OFF_BIH0; const float* bhh=Wall+OFF_BHH0;
  float h2=0.f;
  for(int l=0;l<3;l++){
    float hv = hs[l*B_*DD + row*DD + lane];
    float cv = cs[l*B_*DD + row*DD + lane];
    hbuf[g8][lane]=hv;
    float g0=bih[lane]+bhh[lane];
    float g1=bih[lane+32]+bhh[lane+32];
    float g2=bih[lane+64]+bhh[lane+64];
    float g3=bih[lane+96]+bhh[lane+96];
    for(int k=0;k<xdim;k++){
      float xk=xbuf[g8][k];
      g0=__fmaf_rn(Wih[lane*xdim+k],      xk, g0);
      g1=__fmaf_rn(Wih[(lane+32)*xdim+k], xk, g1);
      g2=__fmaf_rn(Wih[(lane+64)*xdim+k], xk, g2);
      g3=__fmaf_rn(Wih[(lane+96)*xdim+k], xk, g3);
    }
    #pragma unroll 4
    for(int k=0;k<32;k++){
      float hk=hbuf[g8][k];
      g0=__fmaf_rn(Whh[lane*32+k],      hk, g0);
      g1=__fmaf_rn(Whh[(lane+32)*32+k], hk, g1);
      g2=__fmaf_rn(Whh[(lane+64)*32+k], hk, g2);
      g3=__fmaf_rn(Whh[(lane+96)*32+k], hk, g3);
    }
    float iv=sigm(g0), fv=sigm(g1), gv=tanhfast(g2), ov=sigm(g3);
    float c2 = fv*cv + iv*gv;
    h2 = ov*tanhfast(c2);
    cs[l*B_*DD+row*DD+lane]=c2;
    hs[l*B_*DD+row*DD+lane]=h2;
    xbuf[g8][lane]=h2;
    xdim=32;
    if(l==0){ Wih=Wall+OFF_WIH12; Whh=Wall+OFF_WHH12; bih=Wall+OFF_BIH12; bhh=Wall+OFF_BHH12; }
    else    { Wih+=128*32; Whh+=128*32; bih+=128; bhh+=128; }
  }
  qstar[row*64+lane]=h2;   // q part
}

// ---------------- attention logits e[n] = <out[n], q[g[n]]> ----------------
__global__ void k_e(const float* __restrict__ out, const float* __restrict__ qstar,
                    const int* __restrict__ gid, float* __restrict__ ev){
  int t = blockIdx.x*blockDim.x + threadIdx.x;
  int n = t>>5, lane = t&31;
  if(n >= N_) return;
  int g = gid[n]; if((unsigned)g>=(unsigned)B_) g=0;
  float v = out[(size_t)n*DD+lane] * qstar[g*64+lane];
  #pragma unroll
  for(int o=16;o>0;o>>=1) v += __shfl_xor(v, o, 32);
  if(lane==0) ev[n]=v;
}

// ---------------- per-graph softmax + weighted sum -> q_star r part ----------------
__global__ void k_attn(const float* __restrict__ ev, const float* __restrict__ out,
                       const int* __restrict__ goff, float* __restrict__ qstar){
  int g=blockIdx.x, t=threadIdx.x;
  int s0=goff[g], s1=goff[g+1];
  if(s0<0) s0=0; if(s1>N_) s1=N_;
  __shared__ float red[256];
  float mx=-INFINITY;
  for(int i=s0+t;i<s1;i+=256) mx=fmaxf(mx,ev[i]);
  red[t]=mx; __syncthreads();
  for(int o=128;o>0;o>>=1){ if(t<o) red[t]=fmaxf(red[t],red[t+o]); __syncthreads(); }
  mx=red[0]; __syncthreads();
  float sm=0.f;
  for(int i=s0+t;i<s1;i+=256) sm+=__expf(ev[i]-mx);
  red[t]=sm; __syncthreads();
  for(int o=128;o>0;o>>=1){ if(t<o) red[t]+=red[t+o]; __syncthreads(); }
  sm=red[0]; __syncthreads();
  float inv = (sm>0.f) ? 1.f/sm : 0.f;
  int grp=t>>5, lane=t&31;
  float acc=0.f;
  for(int i=s0+grp;i<s1;i+=8){
    float w=__expf(ev[i]-mx);
    acc=__fmaf_rn(w, out[(size_t)i*DD+lane], acc);
  }
  red[grp*32+lane]=acc; __syncthreads();
  if(t<32){
    float s=0.f;
    #pragma unroll
    for(int k=0;k<8;k++) s+=red[k*32+t];
    qstar[g*64+DD+t]=s*inv;
  }
}

// ---------------- readout: relu(qstar@Wr1.T+br1)@Wr2.T+br2 -> out (dtype per flag) --
__global__ void k_read(const float* __restrict__ Wall, const float* __restrict__ qstar,
                       void* __restrict__ op, const int* __restrict__ flag){
  int t=threadIdx.x; int g8=t>>5; int lane=t&31;
  int row = blockIdx.x*8 + g8;
  __shared__ float xb[8][64];
  __shared__ float yb[8][32];
  xb[g8][lane]=qstar[row*64+lane];
  xb[g8][lane+32]=qstar[row*64+32+lane];
  const float* Wr1=Wall+OFF_WR1;
  float s=Wall[OFF_BR1+lane];
  #pragma unroll 8
  for(int k=0;k<64;k++) s=__fmaf_rn(Wr1[lane*64+k], xb[g8][k], s);
  yb[g8][lane]=fmaxf(s,0.f);
  const float* Wr2=Wall+OFF_WR2;
  float o=Wall[OFF_BR2+lane];
  #pragma unroll 8
  for(int k=0;k<32;k++) o=__fmaf_rn(Wr2[lane*32+k], yb[g8][k], o);
  if(flag[0]) ((__hip_bfloat16*)op)[row*32+lane]=__float2bfloat16(o);
  else        ((float*)op)[row*32+lane]=o;
}

extern "C" void kernel_launch(void* const* d_in, const int* in_sizes, int n_in,
                              void* d_out, int out_size, void* d_ws, size_t ws_size,
                              hipStream_t stream) {
  const int* nt  = (const int*)d_in[0];
  const int* src = (const int*)d_in[1];
  const int* dst = (const int*)d_in[2];
  const int* gid = (const int*)d_in[3];
  float* W = (float*)d_ws;
  char* base = (char*)d_ws;
  int* I = (int*)(base + INT_BASE);
  float* qstar = W+OFF_QSTAR; float* hs = W+OFF_HS; float* cs = W+OFF_CS;
  float* out = W+OFF_OUT; float* agg = W+OFF_AGG; float* ev = W+OFF_EV;
  int* deg=I+I_DEG; int* gcnt=I+I_GCNT; int* noff=I+I_NOFF; int* cursor=I+I_CURSOR;
  int* goff=I+I_GOFF; int* bsum=I+I_BSUM; int* boff=I+I_BOFF; int* csr=I+I_CSR;
  int* flag=I+I_FLAG;

  // zero: q_star + hs + cs (floats), deg + gcnt (ints, adjacent)
  hipMemsetAsync(qstar, 0, (size_t)(OFF_OUT-OFF_QSTAR)*4, stream);
  hipMemsetAsync(deg, 0, (size_t)(N_+B_)*4, stream);

  k_detect<<<1,64,0,stream>>>((const unsigned int*)d_in[4], flag);

  PrepArgs pa;
  const int sidx[22]={4,5,6,7,8,9,10,11,12,13,14,15,16,17,18,19,20,21,22,23,7,5};
  const int offs[22]={OFF_EMB,OFF_W0,OFF_B0,OFF_WM,OFF_WIHG,OFF_WHHG,OFF_BIHG,OFF_BHHG,
                      OFF_WIH0,OFF_WHH0,OFF_BIH0,OFF_BHH0,OFF_WIH12,OFF_WHH12,OFF_BIH12,
                      OFF_BHH12,OFF_WR1,OFF_BR1,OFF_WR2,OFF_BR2,OFF_WMT,OFF_W0T};
  const int szs[22]={3232,1024,32,1024,3072,3072,96,96,8192,4096,128,128,8192,8192,256,256,
                     2048,32,1024,32,1024,1024};
  for(int i=0;i<22;i++){ pa.s[i]=d_in[sidx[i]]; pa.off[i]=offs[i]; pa.sz[i]=szs[i]; }
  hipLaunchKernelGGL(k_prep, dim3(32,22), dim3(256), 0, stream, pa, W, flag);

  k_lin0<<<782,256,0,stream>>>(nt, W, out);
  k_deg<<<12500,256,0,stream>>>(dst, deg);
  k_gcnt<<<782,256,0,stream>>>(gid, gcnt);
  k_scanA<<<196,1024,0,stream>>>(deg, cursor, bsum);       // cursor <- inclusive scan
  k_scanB<<<1,256,0,stream>>>(bsum, boff);
  k_scanC<<<196,1024,0,stream>>>(deg, boff, noff, cursor); // noff/cursor <- exclusive
  k_goff<<<1,512,0,stream>>>(gcnt, goff);
  k_scatter<<<12500,256,0,stream>>>(src, dst, cursor, csr);

  for(int s=0;s<6;s++){
    k_agg<<<25000,256,0,stream>>>(noff, deg, csr, out, agg);
    k_node<<<782,256,0,stream>>>(W, agg, out);
  }
  for(int s=0;s<6;s++){
    k_lstm<<<64,256,0,stream>>>(W, qstar, hs, cs);
    k_e<<<25000,256,0,stream>>>(out, qstar, gid, ev);
    k_attn<<<512,256,0,stream>>>(ev, out, goff, qstar);
  }
  k_read<<<64,256,0,stream>>>(W, qstar, d_out, flag);
}

// Round 4
// 2280.099 us; speedup vs baseline: 1.1843x; 1.1843x over previous
//
#include <hip/hip_runtime.h>
#include <hip/hip_bf16.h>

#define DD 32
constexpr int N_ = 200000;
constexpr int E_ = 3200000;
constexpr int B_ = 512;

// ---------------- workspace layout (float offsets) ----------------
constexpr int OFF_EMB=0, OFF_W0=3232, OFF_B0=4256, OFF_WM=4288, OFF_WIHG=5312,
  OFF_WHHG=8384, OFF_BIHG=11456, OFF_BHHG=11552, OFF_WIH0=11648, OFF_WHH0=19840,
  OFF_BIH0=23936, OFF_BHH0=24064, OFF_WIH12=24192, OFF_WHH12=32384, OFF_BIH12=40576,
  OFF_BHH12=40832, OFF_WR1=41088, OFF_BR1=43136, OFF_WR2=43168, OFF_BR2=44192,
  OFF_WMT=44224, OFF_W0T=45248, OFF_WIHGT=46272, OFF_WHHGT=49344;
constexpr int OFF_QSTAR=52416;              // B*64 = 32768
constexpr int OFF_HS=85184;                 // 3*B*32 = 49152
constexpr int OFF_CS=134336;                // 49152
constexpr int OFF_EV=183488;                // N floats
constexpr int OFF_OUT0=383488;              // N*32 fp32
constexpr long OFF_OUT1=6783488L;           // N*32 fp32 (double buffer)
constexpr long FLOAT_END=13183488L;
constexpr size_t INT_BASE = (size_t)FLOAT_END*4;   // byte offset, 256B aligned
// int offsets (in ints, from INT_BASE)
constexpr int I_DEG=0, I_GCNT=200000, I_NOFF=200512, I_CURSOR=400512, I_GOFF=600512,
  I_BSUM=601088, I_BOFF=601344, I_CSR=601600;      // csr: E ints
constexpr int I_FLAG=3801600;

__device__ __forceinline__ float bf2f(unsigned short u){ return __uint_as_float(((unsigned)u)<<16); }
__device__ __forceinline__ float sigm(float x){ return 1.0f/(1.0f+__expf(-x)); }
__device__ __forceinline__ float tanhfast(float x){ return 1.0f - 2.0f/(__expf(2.0f*x)+1.0f); }

// ---------------- input-dtype detection ----------------
// emb row 0 is all zeros (padding_idx=0). Bytes 64..127 of the emb buffer:
//   fp32 mode: second half of row 0 -> all zero;  bf16 mode: row 1 -> nonzero
__global__ void k_detect(const unsigned int* __restrict__ emb_raw, int* __restrict__ flag){
  if(threadIdx.x==0){
    unsigned v=0;
    for(int i=16;i<32;i++) v |= emb_raw[i];
    flag[0] = v ? 1 : 0;   // 1 = bf16 inputs, 0 = f32 inputs
  }
}

// ---------------- weight prep: (bf16|f32) -> fp32, optional [R x 32] transpose ------
struct PrepArgs { const void* s[24]; int off[24]; int sz[24]; int trR[24]; };

__global__ void k_prep(PrepArgs a, float* __restrict__ W, const int* __restrict__ flag){
  int bf = flag[0];
  int seg = blockIdx.y;
  int i = blockIdx.x*256 + threadIdx.x;
  if(i >= a.sz[seg]) return;
  int R = a.trR[seg];                       // 0: copy; else src is [R x 32], dst [32 x R]
  int sidx = R ? ((i%R)*32 + i/R) : i;
  float v = bf ? bf2f(((const unsigned short*)a.s[seg])[sidx])
               : ((const float*)a.s[seg])[sidx];
  W[a.off[seg]+i] = v;
}

// ---------------- lin0: out[n] = relu(W0 @ emb[node_type[n]] + b0) ----------------
__global__ void k_lin0(const int* __restrict__ nt, const float* __restrict__ Wall,
                       float* __restrict__ out){
  int n = blockIdx.x*blockDim.x + threadIdx.x;
  if(n >= N_) return;
  const float* er  = Wall + OFF_EMB + nt[n]*DD;
  const float* W0T = Wall + OFF_W0T;
  const float* b0  = Wall + OFF_B0;
  float m[DD];
  #pragma unroll
  for(int j=0;j<DD;j++) m[j]=b0[j];
  #pragma unroll 4
  for(int k=0;k<DD;k++){
    float xk = er[k];
    #pragma unroll
    for(int j=0;j<DD;j++) m[j] = __fmaf_rn(W0T[k*DD+j], xk, m[j]);
  }
  float4* o4 = (float4*)(out + (size_t)n*DD);
  #pragma unroll
  for(int q=0;q<DD/4;q++){
    float4 v; v.x=fmaxf(m[q*4+0],0.f); v.y=fmaxf(m[q*4+1],0.f);
    v.z=fmaxf(m[q*4+2],0.f); v.w=fmaxf(m[q*4+3],0.f);
    o4[q]=v;
  }
}

// ---------------- CSR build ----------------
__global__ void k_deg(const int* __restrict__ dst, int* __restrict__ deg){
  int e = blockIdx.x*blockDim.x + threadIdx.x;
  if(e < E_) atomicAdd(&deg[dst[e]], 1);
}
__global__ void k_gcnt(const int* __restrict__ gid, int* __restrict__ gcnt){
  int n = blockIdx.x*blockDim.x + threadIdx.x;
  if(n < N_) atomicAdd(&gcnt[gid[n]], 1);
}
__global__ void __launch_bounds__(1024) k_scanA(const int* __restrict__ deg,
                       int* __restrict__ incl, int* __restrict__ bsum){
  __shared__ int sh[1024];
  int g = blockIdx.x*1024 + threadIdx.x;
  int v = (g < N_) ? deg[g] : 0;
  sh[threadIdx.x]=v; __syncthreads();
  for(int o=1;o<1024;o<<=1){
    int a = (threadIdx.x>=o) ? sh[threadIdx.x-o] : 0;
    __syncthreads();
    sh[threadIdx.x]+=a;
    __syncthreads();
  }
  if(g < N_) incl[g]=sh[threadIdx.x];
  if(threadIdx.x==1023) bsum[blockIdx.x]=sh[1023];
}
__global__ void k_scanB(const int* __restrict__ bsum, int* __restrict__ boff){
  __shared__ int sh[256];
  int t=threadIdx.x;
  int v=(t<196)?bsum[t]:0;
  sh[t]=v; __syncthreads();
  for(int o=1;o<256;o<<=1){
    int a=(t>=o)?sh[t-o]:0; __syncthreads(); sh[t]+=a; __syncthreads();
  }
  if(t<196) boff[t]=sh[t]-v;   // exclusive
}
__global__ void __launch_bounds__(1024) k_scanC(const int* __restrict__ deg,
                       const int* __restrict__ boff, int* __restrict__ noff,
                       int* __restrict__ incl_cursor){
  int g = blockIdx.x*1024 + threadIdx.x;
  if(g >= N_) return;
  int ex = incl_cursor[g] - deg[g] + boff[g>>10];
  noff[g]=ex; incl_cursor[g]=ex;   // cursor = exclusive offset
}
__global__ void k_goff(const int* __restrict__ gcnt, int* __restrict__ goff){
  __shared__ int sh[512];
  int t=threadIdx.x;
  int v=gcnt[t]; sh[t]=v; __syncthreads();
  for(int o=1;o<512;o<<=1){
    int a=(t>=o)?sh[t-o]:0; __syncthreads(); sh[t]+=a; __syncthreads();
  }
  goff[t+1]=sh[t];
  if(t==0) goff[0]=0;
}
__global__ void k_scatter(const int* __restrict__ src, const int* __restrict__ dst,
                          int* __restrict__ cursor, int* __restrict__ csr){
  int e = blockIdx.x*blockDim.x + threadIdx.x;
  if(e >= E_) return;
  int p = atomicAdd(&cursor[dst[e]], 1);
  csr[p] = src[e];
}

// ---- fused step: gather-sum (fp32, double-buffered) -> Wm+relu -> GRU -> nxt ----
__global__ void k_step(const float* __restrict__ Wall, const int* __restrict__ noff,
                       const int* __restrict__ deg, const int* __restrict__ csr,
                       const float* __restrict__ cur, float* __restrict__ nxt){
  int t = blockIdx.x*blockDim.x + threadIdx.x;
  int n = t>>5, lane = t&31;
  if(n >= N_) return;
  int s0 = noff[n], len = deg[n];
  float acc = 0.f;
  int i = 0;
  for(; i+8<=len; i+=8){
    int i0=csr[s0+i+0], i1=csr[s0+i+1], i2=csr[s0+i+2], i3=csr[s0+i+3];
    int i4=csr[s0+i+4], i5=csr[s0+i+5], i6=csr[s0+i+6], i7=csr[s0+i+7];
    float v0=cur[(size_t)i0*DD+lane], v1=cur[(size_t)i1*DD+lane];
    float v2=cur[(size_t)i2*DD+lane], v3=cur[(size_t)i3*DD+lane];
    float v4=cur[(size_t)i4*DD+lane], v5=cur[(size_t)i5*DD+lane];
    float v6=cur[(size_t)i6*DD+lane], v7=cur[(size_t)i7*DD+lane];
    acc += ((v0+v1)+(v2+v3)) + ((v4+v5)+(v6+v7));
  }
  for(; i<len; i++)
    acc += cur[(size_t)csr[s0+i]*DD + lane];
  // m[lane] = relu( sum_k Wm[lane,k] * acc_k )  via WmT (coalesced) + shfl broadcast
  const float* WmT = Wall + OFF_WMT;
  float m = 0.f;
  #pragma unroll
  for(int k=0;k<DD;k++)
    m = __fmaf_rn(WmT[k*DD+lane], __shfl(acc,k,32), m);
  m = fmaxf(m, 0.f);
  float h = cur[(size_t)n*DD + lane];
  // GRU gates via transposed weights: W*T[k*96 + gate*32 + lane]
  const float* WihT = Wall + OFF_WIHGT;
  const float* WhhT = Wall + OFF_WHHGT;
  float a_r  = Wall[OFF_BIHG+lane]      + Wall[OFF_BHHG+lane];
  float a_z  = Wall[OFF_BIHG+DD+lane]   + Wall[OFF_BHHG+DD+lane];
  float a_ni = Wall[OFF_BIHG+2*DD+lane];
  float a_nh = Wall[OFF_BHHG+2*DD+lane];
  #pragma unroll 4
  for(int k=0;k<DD;k++){
    float mk = __shfl(m,k,32), hk = __shfl(h,k,32);
    const float* wi = WihT + k*96;
    const float* wh = WhhT + k*96;
    a_r  = __fmaf_rn(wi[lane],      mk, a_r);
    a_r  = __fmaf_rn(wh[lane],      hk, a_r);
    a_z  = __fmaf_rn(wi[DD+lane],   mk, a_z);
    a_z  = __fmaf_rn(wh[DD+lane],   hk, a_z);
    a_ni = __fmaf_rn(wi[2*DD+lane], mk, a_ni);
    a_nh = __fmaf_rn(wh[2*DD+lane], hk, a_nh);
  }
  float r = sigm(a_r), z = sigm(a_z);
  float nn = tanhfast(a_ni + r*a_nh);
  nxt[(size_t)n*DD+lane] = (1.f-z)*nn + z*h;
}

// ---------------- Set2Set: 3-layer LSTM (rows independent) ----------------
__global__ void k_lstm(const float* __restrict__ Wall, float* __restrict__ qstar,
                       float* __restrict__ hs, float* __restrict__ cs){
  int t=threadIdx.x; int g8=t>>5; int lane=t&31;
  int row = blockIdx.x*8 + g8;
  __shared__ float xbuf[8][64];
  __shared__ float hbuf[8][32];
  xbuf[g8][lane]    = qstar[row*64+lane];
  xbuf[g8][lane+32] = qstar[row*64+32+lane];
  int xdim=64;
  const float* Wih=Wall+OFF_WIH0; const float* Whh=Wall+OFF_WHH0;
  const float* bih=Wall+OFF_BIH0; const float* bhh=Wall+OFF_BHH0;
  float h2=0.f;
  for(int l=0;l<3;l++){
    float hv = hs[l*B_*DD + row*DD + lane];
    float cv = cs[l*B_*DD + row*DD + lane];
    hbuf[g8][lane]=hv;
    float g0=bih[lane]+bhh[lane];
    float g1=bih[lane+32]+bhh[lane+32];
    float g2=bih[lane+64]+bhh[lane+64];
    float g3=bih[lane+96]+bhh[lane+96];
    for(int k=0;k<xdim;k++){
      float xk=xbuf[g8][k];
      g0=__fmaf_rn(Wih[lane*xdim+k],      xk, g0);
      g1=__fmaf_rn(Wih[(lane+32)*xdim+k], xk, g1);
      g2=__fmaf_rn(Wih[(lane+64)*xdim+k], xk, g2);
      g3=__fmaf_rn(Wih[(lane+96)*xdim+k], xk, g3);
    }
    #pragma unroll 4
    for(int k=0;k<32;k++){
      float hk=hbuf[g8][k];
      g0=__fmaf_rn(Whh[lane*32+k],      hk, g0);
      g1=__fmaf_rn(Whh[(lane+32)*32+k], hk, g1);
      g2=__fmaf_rn(Whh[(lane+64)*32+k], hk, g2);
      g3=__fmaf_rn(Whh[(lane+96)*32+k], hk, g3);
    }
    float iv=sigm(g0), fv=sigm(g1), gv=tanhfast(g2), ov=sigm(g3);
    float c2 = fv*cv + iv*gv;
    h2 = ov*tanhfast(c2);
    cs[l*B_*DD+row*DD+lane]=c2;
    hs[l*B_*DD+row*DD+lane]=h2;
    xbuf[g8][lane]=h2;
    xdim=32;
    if(l==0){ Wih=Wall+OFF_WIH12; Whh=Wall+OFF_WHH12; bih=Wall+OFF_BIH12; bhh=Wall+OFF_BHH12; }
    else    { Wih+=128*32; Whh+=128*32; bih+=128; bhh+=128; }
  }
  qstar[row*64+lane]=h2;   // q part
}

// ------- fused attention: logits + softmax + weighted sum (block per graph) -------
__global__ void k_eattn(const float* __restrict__ out, const int* __restrict__ goff,
                        float* __restrict__ ev, float* __restrict__ qstar){
  int g=blockIdx.x, t=threadIdx.x;
  int s0=goff[g], s1=goff[g+1];
  int hw=t>>5, lane=t&31;
  __shared__ float red[256];
  float q = qstar[g*64+lane];
  float lmax = -INFINITY;
  for(int i=s0+hw; i<s1; i+=8){
    float v = out[(size_t)i*DD+lane]*q;
    #pragma unroll
    for(int o=16;o>0;o>>=1) v += __shfl_xor(v,o,32);
    if(lane==0) ev[i]=v;
    lmax = fmaxf(lmax, v);
  }
  __threadfence_block();
  red[t]=lmax; __syncthreads();
  for(int o=128;o>0;o>>=1){ if(t<o) red[t]=fmaxf(red[t],red[t+o]); __syncthreads(); }
  float mx=red[0]; __syncthreads();
  float sm=0.f;
  for(int i=s0+t;i<s1;i+=256) sm+=__expf(ev[i]-mx);
  red[t]=sm; __syncthreads();
  for(int o=128;o>0;o>>=1){ if(t<o) red[t]+=red[t+o]; __syncthreads(); }
  sm=red[0]; __syncthreads();
  float inv = (sm>0.f) ? 1.f/sm : 0.f;
  float acc=0.f;
  for(int i=s0+hw;i<s1;i+=8){
    float w=__expf(ev[i]-mx);
    acc=__fmaf_rn(w, out[(size_t)i*DD+lane], acc);
  }
  red[hw*32+lane]=acc; __syncthreads();
  if(t<32){
    float s=0.f;
    #pragma unroll
    for(int k=0;k<8;k++) s+=red[k*32+t];
    qstar[g*64+DD+t]=s*inv;
  }
}

// ---------------- readout: relu(qstar@Wr1.T+br1)@Wr2.T+br2 -> out (dtype per flag) --
__global__ void k_read(const float* __restrict__ Wall, const float* __restrict__ qstar,
                       void* __restrict__ op, const int* __restrict__ flag){
  int t=threadIdx.x; int g8=t>>5; int lane=t&31;
  int row = blockIdx.x*8 + g8;
  __shared__ float xb[8][64];
  __shared__ float yb[8][32];
  xb[g8][lane]=qstar[row*64+lane];
  xb[g8][lane+32]=qstar[row*64+32+lane];
  const float* Wr1=Wall+OFF_WR1;
  float s=Wall[OFF_BR1+lane];
  #pragma unroll 8
  for(int k=0;k<64;k++) s=__fmaf_rn(Wr1[lane*64+k], xb[g8][k], s);
  yb[g8][lane]=fmaxf(s,0.f);
  const float* Wr2=Wall+OFF_WR2;
  float o=Wall[OFF_BR2+lane];
  #pragma unroll 8
  for(int k=0;k<32;k++) o=__fmaf_rn(Wr2[lane*32+k], yb[g8][k], o);
  if(flag[0]) ((__hip_bfloat16*)op)[row*32+lane]=__float2bfloat16(o);
  else        ((float*)op)[row*32+lane]=o;
}

extern "C" void kernel_launch(void* const* d_in, const int* in_sizes, int n_in,
                              void* d_out, int out_size, void* d_ws, size_t ws_size,
                              hipStream_t stream) {
  const int* nt  = (const int*)d_in[0];
  const int* src = (const int*)d_in[1];
  const int* dst = (const int*)d_in[2];
  const int* gid = (const int*)d_in[3];
  float* W = (float*)d_ws;
  char* base = (char*)d_ws;
  int* I = (int*)(base + INT_BASE);
  float* qstar = W+OFF_QSTAR; float* hs = W+OFF_HS; float* cs = W+OFF_CS;
  float* ev = W+OFF_EV;
  float* out0 = W+OFF_OUT0; float* out1 = W+OFF_OUT1;
  int* deg=I+I_DEG; int* gcnt=I+I_GCNT; int* noff=I+I_NOFF; int* cursor=I+I_CURSOR;
  int* goff=I+I_GOFF; int* bsum=I+I_BSUM; int* boff=I+I_BOFF; int* csr=I+I_CSR;
  int* flag=I+I_FLAG;

  // zero: q_star + hs + cs (floats), deg + gcnt (ints, adjacent)
  hipMemsetAsync(qstar, 0, (size_t)(OFF_EV-OFF_QSTAR)*4, stream);
  hipMemsetAsync(deg, 0, (size_t)(N_+B_)*4, stream);

  k_detect<<<1,64,0,stream>>>((const unsigned int*)d_in[4], flag);

  PrepArgs pa;
  const int sidx[24]={4,5,6,7,8,9,10,11,12,13,14,15,16,17,18,19,20,21,22,23,7,5,8,9};
  const int offs[24]={OFF_EMB,OFF_W0,OFF_B0,OFF_WM,OFF_WIHG,OFF_WHHG,OFF_BIHG,OFF_BHHG,
                      OFF_WIH0,OFF_WHH0,OFF_BIH0,OFF_BHH0,OFF_WIH12,OFF_WHH12,OFF_BIH12,
                      OFF_BHH12,OFF_WR1,OFF_BR1,OFF_WR2,OFF_BR2,OFF_WMT,OFF_W0T,
                      OFF_WIHGT,OFF_WHHGT};
  const int szs[24]={3232,1024,32,1024,3072,3072,96,96,8192,4096,128,128,8192,8192,256,256,
                     2048,32,1024,32,1024,1024,3072,3072};
  const int trR[24]={0,0,0,0,0,0,0,0,0,0,0,0,0,0,0,0,0,0,0,0,32,32,96,96};
  for(int i=0;i<24;i++){ pa.s[i]=d_in[sidx[i]]; pa.off[i]=offs[i]; pa.sz[i]=szs[i]; pa.trR[i]=trR[i]; }
  hipLaunchKernelGGL(k_prep, dim3(32,24), dim3(256), 0, stream, pa, W, flag);

  k_lin0<<<782,256,0,stream>>>(nt, W, out0);
  k_deg<<<12500,256,0,stream>>>(dst, deg);
  k_gcnt<<<782,256,0,stream>>>(gid, gcnt);
  k_scanA<<<196,1024,0,stream>>>(deg, cursor, bsum);       // cursor <- inclusive scan
  k_scanB<<<1,256,0,stream>>>(bsum, boff);
  k_scanC<<<196,1024,0,stream>>>(deg, boff, noff, cursor); // noff/cursor <- exclusive
  k_goff<<<1,512,0,stream>>>(gcnt, goff);
  k_scatter<<<12500,256,0,stream>>>(src, dst, cursor, csr);

  // 6 MP steps, double-buffered (even count -> final features land in out0)
  float* cur = out0; float* nxt = out1;
  for(int s=0;s<6;s++){
    k_step<<<25000,256,0,stream>>>(W, noff, deg, csr, cur, nxt);
    float* tmp = cur; cur = nxt; nxt = tmp;
  }
  for(int s=0;s<6;s++){
    k_lstm<<<64,256,0,stream>>>(W, qstar, hs, cs);
    k_eattn<<<512,256,0,stream>>>(cur, goff, ev, qstar);
  }
  k_read<<<64,256,0,stream>>>(W, qstar, d_out, flag);
}

// Round 5
// 2269.617 us; speedup vs baseline: 1.1898x; 1.0046x over previous
//
#include <hip/hip_runtime.h>
#include <hip/hip_bf16.h>
#include <hip/hip_fp16.h>

#define DD 32
constexpr int N_ = 200000;
constexpr int E_ = 3200000;
constexpr int B_ = 512;

// ---------------- workspace layout (float offsets) ----------------
constexpr int OFF_EMB=0, OFF_W0=3232, OFF_B0=4256, OFF_WM=4288, OFF_WIHG=5312,
  OFF_WHHG=8384, OFF_BIHG=11456, OFF_BHHG=11552, OFF_WIH0=11648, OFF_WHH0=19840,
  OFF_BIH0=23936, OFF_BHH0=24064, OFF_WIH12=24192, OFF_WHH12=32384, OFF_BIH12=40576,
  OFF_BHH12=40832, OFF_WR1=41088, OFF_BR1=43136, OFF_WR2=43168, OFF_BR2=44192,
  OFF_WMT=44224, OFF_W0T=45248, OFF_WIHGT=46272, OFF_WHHGT=49344;
constexpr int OFF_QSTAR=52416;              // B*64 = 32768
constexpr int OFF_HS=85184;                 // 3*B*32 = 49152
constexpr int OFF_CS=134336;                // 49152
constexpr int OFF_EV=183488;                // N floats
constexpr int OFF_OUT=383488;               // N*32 fp32 (single buffer, in-place)
constexpr long FLOAT_END=6783488L;
constexpr size_t H0_BYTE = (size_t)FLOAT_END*4;            // fp16 mirror A, N*32*2 B
constexpr size_t H1_BYTE = H0_BYTE + (size_t)N_*DD*2;      // fp16 mirror B
constexpr size_t INT_BASE = H1_BYTE + (size_t)N_*DD*2;     // 52733952, 256B aligned
// int offsets (in ints, from INT_BASE)
constexpr int I_DEG=0, I_GCNT=200000, I_NOFF=200512, I_CURSOR=400512, I_GOFF=600512,
  I_BSUM=601088, I_BOFF=601344, I_CSR=601600;      // csr: E ints
constexpr int I_FLAG=3801600;

__device__ __forceinline__ float bf2f(unsigned short u){ return __uint_as_float(((unsigned)u)<<16); }
__device__ __forceinline__ float sigm(float x){ return 1.0f/(1.0f+__expf(-x)); }
__device__ __forceinline__ float tanhfast(float x){ return 1.0f - 2.0f/(__expf(2.0f*x)+1.0f); }

// ---------------- input-dtype detection ----------------
// emb row 0 is all zeros (padding_idx=0). Bytes 64..127 of the emb buffer:
//   fp32 mode: second half of row 0 -> all zero;  bf16 mode: row 1 -> nonzero
__global__ void k_detect(const unsigned int* __restrict__ emb_raw, int* __restrict__ flag){
  if(threadIdx.x==0){
    unsigned v=0;
    for(int i=16;i<32;i++) v |= emb_raw[i];
    flag[0] = v ? 1 : 0;   // 1 = bf16 inputs, 0 = f32 inputs
  }
}

// ---------------- weight prep: (bf16|f32) -> fp32, optional [R x 32] transpose ------
struct PrepArgs { const void* s[24]; int off[24]; int sz[24]; int trR[24]; };

__global__ void k_prep(PrepArgs a, float* __restrict__ W, const int* __restrict__ flag){
  int bf = flag[0];
  int seg = blockIdx.y;
  int i = blockIdx.x*256 + threadIdx.x;
  if(i >= a.sz[seg]) return;
  int R = a.trR[seg];                       // 0: copy; else src is [R x 32], dst [32 x R]
  int sidx = R ? ((i%R)*32 + i/R) : i;
  float v = bf ? bf2f(((const unsigned short*)a.s[seg])[sidx])
               : ((const float*)a.s[seg])[sidx];
  W[a.off[seg]+i] = v;
}

// ---------------- lin0: out[n] = relu(W0 @ emb[node_type[n]] + b0) ----------------
__global__ void k_lin0(const int* __restrict__ nt, const float* __restrict__ Wall,
                       float* __restrict__ out, __half* __restrict__ hmir){
  int n = blockIdx.x*blockDim.x + threadIdx.x;
  if(n >= N_) return;
  const float* er  = Wall + OFF_EMB + nt[n]*DD;
  const float* W0T = Wall + OFF_W0T;
  const float* b0  = Wall + OFF_B0;
  float m[DD];
  #pragma unroll
  for(int j=0;j<DD;j++) m[j]=b0[j];
  #pragma unroll 4
  for(int k=0;k<DD;k++){
    float xk = er[k];
    #pragma unroll
    for(int j=0;j<DD;j++) m[j] = __fmaf_rn(W0T[k*DD+j], xk, m[j]);
  }
  float* orow = out + (size_t)n*DD;
  __half* hrow = hmir + (size_t)n*DD;
  #pragma unroll
  for(int j=0;j<DD;j++){
    float v = fmaxf(m[j],0.f);
    orow[j]=v; hrow[j]=__float2half(v);
  }
}

// ---------------- CSR build ----------------
__global__ void k_deg(const int* __restrict__ dst, int* __restrict__ deg){
  int e = blockIdx.x*blockDim.x + threadIdx.x;
  if(e < E_) atomicAdd(&deg[dst[e]], 1);
}
__global__ void k_gcnt(const int* __restrict__ gid, int* __restrict__ gcnt){
  int n = blockIdx.x*blockDim.x + threadIdx.x;
  if(n < N_) atomicAdd(&gcnt[gid[n]], 1);
}
__global__ void __launch_bounds__(1024) k_scanA(const int* __restrict__ deg,
                       int* __restrict__ incl, int* __restrict__ bsum){
  __shared__ int sh[1024];
  int g = blockIdx.x*1024 + threadIdx.x;
  int v = (g < N_) ? deg[g] : 0;
  sh[threadIdx.x]=v; __syncthreads();
  for(int o=1;o<1024;o<<=1){
    int a = (threadIdx.x>=o) ? sh[threadIdx.x-o] : 0;
    __syncthreads();
    sh[threadIdx.x]+=a;
    __syncthreads();
  }
  if(g < N_) incl[g]=sh[threadIdx.x];
  if(threadIdx.x==1023) bsum[blockIdx.x]=sh[1023];
}
__global__ void k_scanB(const int* __restrict__ bsum, int* __restrict__ boff){
  __shared__ int sh[256];
  int t=threadIdx.x;
  int v=(t<196)?bsum[t]:0;
  sh[t]=v; __syncthreads();
  for(int o=1;o<256;o<<=1){
    int a=(t>=o)?sh[t-o]:0; __syncthreads(); sh[t]+=a; __syncthreads();
  }
  if(t<196) boff[t]=sh[t]-v;   // exclusive
}
__global__ void __launch_bounds__(1024) k_scanC(const int* __restrict__ deg,
                       const int* __restrict__ boff, int* __restrict__ noff,
                       int* __restrict__ incl_cursor){
  int g = blockIdx.x*1024 + threadIdx.x;
  if(g >= N_) return;
  int ex = incl_cursor[g] - deg[g] + boff[g>>10];
  noff[g]=ex; incl_cursor[g]=ex;   // cursor = exclusive offset
}
__global__ void k_goff(const int* __restrict__ gcnt, int* __restrict__ goff){
  __shared__ int sh[512];
  int t=threadIdx.x;
  int v=gcnt[t]; sh[t]=v; __syncthreads();
  for(int o=1;o<512;o<<=1){
    int a=(t>=o)?sh[t-o]:0; __syncthreads(); sh[t]+=a; __syncthreads();
  }
  goff[t+1]=sh[t];
  if(t==0) goff[0]=0;
}
__global__ void k_scatter(const int* __restrict__ src, const int* __restrict__ dst,
                          int* __restrict__ cursor, int* __restrict__ csr){
  int e = blockIdx.x*blockDim.x + threadIdx.x;
  if(e >= E_) return;
  int p = atomicAdd(&cursor[dst[e]], 1);
  csr[p] = src[e];
}

// ---- fused step: gather-sum (fp16 mirror) -> Wm+relu -> GRU (fp32 in-place) ----
// fp32 `out` is read/written only at each node's own row (no cross-thread sharing);
// the gather reads the double-buffered fp16 mirror `curh`, results go to `nxth`.
__global__ void k_step(const float* __restrict__ Wall, const int* __restrict__ noff,
                       const int* __restrict__ deg, const int* __restrict__ csr,
                       float* __restrict__ out,
                       const __half* __restrict__ curh, __half* __restrict__ nxth){
  int t = blockIdx.x*blockDim.x + threadIdx.x;
  int n = t>>5, lane = t&31;
  if(n >= N_) return;
  int s0 = noff[n], len = deg[n];
  float acc = 0.f;
  int i = 0;
  for(; i+8<=len; i+=8){
    int i0=csr[s0+i+0], i1=csr[s0+i+1], i2=csr[s0+i+2], i3=csr[s0+i+3];
    int i4=csr[s0+i+4], i5=csr[s0+i+5], i6=csr[s0+i+6], i7=csr[s0+i+7];
    float v0=__half2float(curh[(size_t)i0*DD+lane]);
    float v1=__half2float(curh[(size_t)i1*DD+lane]);
    float v2=__half2float(curh[(size_t)i2*DD+lane]);
    float v3=__half2float(curh[(size_t)i3*DD+lane]);
    float v4=__half2float(curh[(size_t)i4*DD+lane]);
    float v5=__half2float(curh[(size_t)i5*DD+lane]);
    float v6=__half2float(curh[(size_t)i6*DD+lane]);
    float v7=__half2float(curh[(size_t)i7*DD+lane]);
    acc += ((v0+v1)+(v2+v3)) + ((v4+v5)+(v6+v7));
  }
  for(; i<len; i++)
    acc += __half2float(curh[(size_t)csr[s0+i]*DD + lane]);
  // m[lane] = relu( sum_k Wm[lane,k] * acc_k )  via WmT (coalesced) + shfl broadcast
  const float* WmT = Wall + OFF_WMT;
  float m = 0.f;
  #pragma unroll
  for(int k=0;k<DD;k++)
    m = __fmaf_rn(WmT[k*DD+lane], __shfl(acc,k,32), m);
  m = fmaxf(m, 0.f);
  float h = out[(size_t)n*DD + lane];
  // GRU gates via transposed weights: W*T[k*96 + gate*32 + lane]
  const float* WihT = Wall + OFF_WIHGT;
  const float* WhhT = Wall + OFF_WHHGT;
  float a_r  = Wall[OFF_BIHG+lane]      + Wall[OFF_BHHG+lane];
  float a_z  = Wall[OFF_BIHG+DD+lane]   + Wall[OFF_BHHG+DD+lane];
  float a_ni = Wall[OFF_BIHG+2*DD+lane];
  float a_nh = Wall[OFF_BHHG+2*DD+lane];
  #pragma unroll 4
  for(int k=0;k<DD;k++){
    float mk = __shfl(m,k,32), hk = __shfl(h,k,32);
    const float* wi = WihT + k*96;
    const float* wh = WhhT + k*96;
    a_r  = __fmaf_rn(wi[lane],      mk, a_r);
    a_r  = __fmaf_rn(wh[lane],      hk, a_r);
    a_z  = __fmaf_rn(wi[DD+lane],   mk, a_z);
    a_z  = __fmaf_rn(wh[DD+lane],   hk, a_z);
    a_ni = __fmaf_rn(wi[2*DD+lane], mk, a_ni);
    a_nh = __fmaf_rn(wh[2*DD+lane], hk, a_nh);
  }
  float r = sigm(a_r), z = sigm(a_z);
  float nn = tanhfast(a_ni + r*a_nh);
  float ho = (1.f-z)*nn + z*h;
  out[(size_t)n*DD+lane] = ho;
  nxth[(size_t)n*DD+lane] = __float2half(ho);
}

// ---------------- Set2Set: 3-layer LSTM (rows independent) ----------------
__global__ void k_lstm(const float* __restrict__ Wall, float* __restrict__ qstar,
                       float* __restrict__ hs, float* __restrict__ cs){
  int t=threadIdx.x; int g8=t>>5; int lane=t&31;
  int row = blockIdx.x*8 + g8;
  __shared__ float xbuf[8][64];
  __shared__ float hbuf[8][32];
  xbuf[g8][lane]    = qstar[row*64+lane];
  xbuf[g8][lane+32] = qstar[row*64+32+lane];
  int xdim=64;
  const float* Wih=Wall+OFF_WIH0; const float* Whh=Wall+OFF_WHH0;
  const float* bih=Wall+OFF_BIH0; const float* bhh=Wall+OFF_BHH0;
  float h2=0.f;
  for(int l=0;l<3;l++){
    float hv = hs[l*B_*DD + row*DD + lane];
    float cv = cs[l*B_*DD + row*DD + lane];
    hbuf[g8][lane]=hv;
    float g0=bih[lane]+bhh[lane];
    float g1=bih[lane+32]+bhh[lane+32];
    float g2=bih[lane+64]+bhh[lane+64];
    float g3=bih[lane+96]+bhh[lane+96];
    for(int k=0;k<xdim;k++){
      float xk=xbuf[g8][k];
      g0=__fmaf_rn(Wih[lane*xdim+k],      xk, g0);
      g1=__fmaf_rn(Wih[(lane+32)*xdim+k], xk, g1);
      g2=__fmaf_rn(Wih[(lane+64)*xdim+k], xk, g2);
      g3=__fmaf_rn(Wih[(lane+96)*xdim+k], xk, g3);
    }
    #pragma unroll 4
    for(int k=0;k<32;k++){
      float hk=hbuf[g8][k];
      g0=__fmaf_rn(Whh[lane*32+k],      hk, g0);
      g1=__fmaf_rn(Whh[(lane+32)*32+k], hk, g1);
      g2=__fmaf_rn(Whh[(lane+64)*32+k], hk, g2);
      g3=__fmaf_rn(Whh[(lane+96)*32+k], hk, g3);
    }
    float iv=sigm(g0), fv=sigm(g1), gv=tanhfast(g2), ov=sigm(g3);
    float c2 = fv*cv + iv*gv;
    h2 = ov*tanhfast(c2);
    cs[l*B_*DD+row*DD+lane]=c2;
    hs[l*B_*DD+row*DD+lane]=h2;
    xbuf[g8][lane]=h2;
    xdim=32;
    if(l==0){ Wih=Wall+OFF_WIH12; Whh=Wall+OFF_WHH12; bih=Wall+OFF_BIH12; bhh=Wall+OFF_BHH12; }
    else    { Wih+=128*32; Whh+=128*32; bih+=128; bhh+=128; }
  }
  qstar[row*64+lane]=h2;   // q part
}

// ------- fused attention: logits + softmax + weighted sum (block per graph) -------
__global__ void k_eattn(const float* __restrict__ out, const int* __restrict__ goff,
                        float* __restrict__ ev, float* __restrict__ qstar){
  int g=blockIdx.x, t=threadIdx.x;
  int s0=goff[g], s1=goff[g+1];
  int hw=t>>5, lane=t&31;
  __shared__ float red[256];
  float q = qstar[g*64+lane];
  float lmax = -INFINITY;
  for(int i=s0+hw; i<s1; i+=8){
    float v = out[(size_t)i*DD+lane]*q;
    #pragma unroll
    for(int o=16;o>0;o>>=1) v += __shfl_xor(v,o,32);
    if(lane==0) ev[i]=v;
    lmax = fmaxf(lmax, v);
  }
  __threadfence_block();
  red[t]=lmax; __syncthreads();
  for(int o=128;o>0;o>>=1){ if(t<o) red[t]=fmaxf(red[t],red[t+o]); __syncthreads(); }
  float mx=red[0]; __syncthreads();
  float sm=0.f;
  for(int i=s0+t;i<s1;i+=256) sm+=__expf(ev[i]-mx);
  red[t]=sm; __syncthreads();
  for(int o=128;o>0;o>>=1){ if(t<o) red[t]+=red[t+o]; __syncthreads(); }
  sm=red[0]; __syncthreads();
  float inv = (sm>0.f) ? 1.f/sm : 0.f;
  float acc=0.f;
  for(int i=s0+hw;i<s1;i+=8){
    float w=__expf(ev[i]-mx);
    acc=__fmaf_rn(w, out[(size_t)i*DD+lane], acc);
  }
  red[hw*32+lane]=acc; __syncthreads();
  if(t<32){
    float s=0.f;
    #pragma unroll
    for(int k=0;k<8;k++) s+=red[k*32+t];
    qstar[g*64+DD+t]=s*inv;
  }
}

// ---------------- readout: relu(qstar@Wr1.T+br1)@Wr2.T+br2 -> out (dtype per flag) --
__global__ void k_read(const float* __restrict__ Wall, const float* __restrict__ qstar,
                       void* __restrict__ op, const int* __restrict__ flag){
  int t=threadIdx.x; int g8=t>>5; int lane=t&31;
  int row = blockIdx.x*8 + g8;
  __shared__ float xb[8][64];
  __shared__ float yb[8][32];
  xb[g8][lane]=qstar[row*64+lane];
  xb[g8][lane+32]=qstar[row*64+32+lane];
  const float* Wr1=Wall+OFF_WR1;
  float s=Wall[OFF_BR1+lane];
  #pragma unroll 8
  for(int k=0;k<64;k++) s=__fmaf_rn(Wr1[lane*64+k], xb[g8][k], s);
  yb[g8][lane]=fmaxf(s,0.f);
  const float* Wr2=Wall+OFF_WR2;
  float o=Wall[OFF_BR2+lane];
  #pragma unroll 8
  for(int k=0;k<32;k++) o=__fmaf_rn(Wr2[lane*32+k], yb[g8][k], o);
  if(flag[0]) ((__hip_bfloat16*)op)[row*32+lane]=__float2bfloat16(o);
  else        ((float*)op)[row*32+lane]=o;
}

extern "C" void kernel_launch(void* const* d_in, const int* in_sizes, int n_in,
                              void* d_out, int out_size, void* d_ws, size_t ws_size,
                              hipStream_t stream) {
  const int* nt  = (const int*)d_in[0];
  const int* src = (const int*)d_in[1];
  const int* dst = (const int*)d_in[2];
  const int* gid = (const int*)d_in[3];
  float* W = (float*)d_ws;
  char* base = (char*)d_ws;
  __half* h0 = (__half*)(base + H0_BYTE);
  __half* h1 = (__half*)(base + H1_BYTE);
  int* I = (int*)(base + INT_BASE);
  float* qstar = W+OFF_QSTAR; float* hs = W+OFF_HS; float* cs = W+OFF_CS;
  float* ev = W+OFF_EV;
  float* out = W+OFF_OUT;
  int* deg=I+I_DEG; int* gcnt=I+I_GCNT; int* noff=I+I_NOFF; int* cursor=I+I_CURSOR;
  int* goff=I+I_GOFF; int* bsum=I+I_BSUM; int* boff=I+I_BOFF; int* csr=I+I_CSR;
  int* flag=I+I_FLAG;

  // zero: q_star + hs + cs (floats), deg + gcnt (ints, adjacent)
  hipMemsetAsync(qstar, 0, (size_t)(OFF_EV-OFF_QSTAR)*4, stream);
  hipMemsetAsync(deg, 0, (size_t)(N_+B_)*4, stream);

  k_detect<<<1,64,0,stream>>>((const unsigned int*)d_in[4], flag);

  PrepArgs pa;
  const int sidx[24]={4,5,6,7,8,9,10,11,12,13,14,15,16,17,18,19,20,21,22,23,7,5,8,9};
  const int offs[24]={OFF_EMB,OFF_W0,OFF_B0,OFF_WM,OFF_WIHG,OFF_WHHG,OFF_BIHG,OFF_BHHG,
                      OFF_WIH0,OFF_WHH0,OFF_BIH0,OFF_BHH0,OFF_WIH12,OFF_WHH12,OFF_BIH12,
                      OFF_BHH12,OFF_WR1,OFF_BR1,OFF_WR2,OFF_BR2,OFF_WMT,OFF_W0T,
                      OFF_WIHGT,OFF_WHHGT};
  const int szs[24]={3232,1024,32,1024,3072,3072,96,96,8192,4096,128,128,8192,8192,256,256,
                     2048,32,1024,32,1024,1024,3072,3072};
  const int trR[24]={0,0,0,0,0,0,0,0,0,0,0,0,0,0,0,0,0,0,0,0,32,32,96,96};
  for(int i=0;i<24;i++){ pa.s[i]=d_in[sidx[i]]; pa.off[i]=offs[i]; pa.sz[i]=szs[i]; pa.trR[i]=trR[i]; }
  hipLaunchKernelGGL(k_prep, dim3(32,24), dim3(256), 0, stream, pa, W, flag);

  k_lin0<<<782,256,0,stream>>>(nt, W, out, h0);
  k_deg<<<12500,256,0,stream>>>(dst, deg);
  k_gcnt<<<782,256,0,stream>>>(gid, gcnt);
  k_scanA<<<196,1024,0,stream>>>(deg, cursor, bsum);       // cursor <- inclusive scan
  k_scanB<<<1,256,0,stream>>>(bsum, boff);
  k_scanC<<<196,1024,0,stream>>>(deg, boff, noff, cursor); // noff/cursor <- exclusive
  k_goff<<<1,512,0,stream>>>(gcnt, goff);
  k_scatter<<<12500,256,0,stream>>>(src, dst, cursor, csr);

  // 6 MP steps: fp32 `out` updated in place; fp16 gather mirror double-buffered
  __half* curh = h0; __half* nxth = h1;
  for(int s=0;s<6;s++){
    k_step<<<25000,256,0,stream>>>(W, noff, deg, csr, out, curh, nxth);
    __half* tmp = curh; curh = nxth; nxth = tmp;
  }
  for(int s=0;s<6;s++){
    k_lstm<<<64,256,0,stream>>>(W, qstar, hs, cs);
    k_eattn<<<512,256,0,stream>>>(out, goff, ev, qstar);
  }
  k_read<<<64,256,0,stream>>>(W, qstar, d_out, flag);
}

// Round 6
// 1999.564 us; speedup vs baseline: 1.3504x; 1.1351x over previous
//
#include <hip/hip_runtime.h>
#include <hip/hip_bf16.h>
#include <hip/hip_fp16.h>

#define DD 32
constexpr int N_ = 200000;
constexpr int E_ = 3200000;
constexpr int B_ = 512;

// ---------------- workspace layout (float offsets) ----------------
constexpr int OFF_EMB=0, OFF_B0=3232, OFF_BIHG=3264, OFF_BHHG=3360, OFF_BIH0=3456,
  OFF_BHH0=3584, OFF_BIH12=3712, OFF_BHH12=3968, OFF_BR1=4224, OFF_BR2=4256,
  OFF_W0T=4288, OFF_WMT=5312, OFF_WIHGT=6336, OFF_WHHGT=9408,
  OFF_WIH0T=12480, OFF_WHH0T=20672, OFF_WIH1T=24768, OFF_WHH1T=28864,
  OFF_WIH2T=32960, OFF_WHH2T=37056, OFF_WR1T=41152, OFF_WR2T=43200;
constexpr int OFF_OUT=44288;                 // N*32 fp32
constexpr long FLOAT_END=6444288L;
constexpr size_t H0_BYTE = (size_t)FLOAT_END*4;            // fp16 mirror A
constexpr size_t H1_BYTE = H0_BYTE + (size_t)N_*DD*2;      // fp16 mirror B
constexpr size_t INT_BASE = H1_BYTE + (size_t)N_*DD*2;     // 51377152, 256B aligned
// int offsets (in ints, from INT_BASE)
constexpr int I_DEG=0, I_GCNT=200000, I_NOFF=200512, I_CURSOR=400512, I_GOFF=600512,
  I_BSUM=601088, I_BOFF=601344, I_CSR=601600;      // csr: E ints
constexpr int I_FLAG=3801600;

__device__ __forceinline__ float bf2f(unsigned short u){ return __uint_as_float(((unsigned)u)<<16); }
__device__ __forceinline__ float sigm(float x){ return 1.0f/(1.0f+__expf(-x)); }
__device__ __forceinline__ float tanhfast(float x){ return 1.0f - 2.0f/(__expf(2.0f*x)+1.0f); }

// ---------------- input-dtype detection ----------------
__global__ void k_detect(const unsigned int* __restrict__ emb_raw, int* __restrict__ flag){
  if(threadIdx.x==0){
    unsigned v=0;
    for(int i=16;i<32;i++) v |= emb_raw[i];
    flag[0] = v ? 1 : 0;   // 1 = bf16 inputs, 0 = f32 inputs
  }
}

// -------- weight prep: (bf16|f32) -> fp32; trR!=0: transpose [R x C] -> [C x R] -----
struct PrepArgs { const void* s[22]; int off[22]; int sz[22]; int trR[22]; int soff[22]; };

__global__ void k_prep(PrepArgs a, float* __restrict__ W, const int* __restrict__ flag){
  int bf = flag[0];
  int seg = blockIdx.y;
  int i = blockIdx.x*256 + threadIdx.x;
  if(i >= a.sz[seg]) return;
  int R = a.trR[seg];
  int sidx;
  if(R){ int C = a.sz[seg]/R; sidx = (i%R)*C + (i/R); } else sidx = i;
  sidx += a.soff[seg];
  float v = bf ? bf2f(((const unsigned short*)a.s[seg])[sidx])
               : ((const float*)a.s[seg])[sidx];
  W[a.off[seg]+i] = v;
}

// ---------------- lin0: out[n] = relu(W0 @ emb[node_type[n]] + b0) ----------------
__global__ void k_lin0(const int* __restrict__ nt, const float* __restrict__ Wall,
                       float* __restrict__ out, __half* __restrict__ hmir){
  int n = blockIdx.x*blockDim.x + threadIdx.x;
  if(n >= N_) return;
  const float* er  = Wall + OFF_EMB + nt[n]*DD;
  const float* W0T = Wall + OFF_W0T;
  const float* b0  = Wall + OFF_B0;
  float m[DD];
  #pragma unroll
  for(int j=0;j<DD;j++) m[j]=b0[j];
  #pragma unroll 4
  for(int k=0;k<DD;k++){
    float xk = er[k];
    #pragma unroll
    for(int j=0;j<DD;j++) m[j] = __fmaf_rn(W0T[k*DD+j], xk, m[j]);
  }
  float* orow = out + (size_t)n*DD;
  __half* hrow = hmir + (size_t)n*DD;
  #pragma unroll
  for(int j=0;j<DD;j++){
    float v = fmaxf(m[j],0.f);
    orow[j]=v; hrow[j]=__float2half(v);
  }
}

// ---------------- CSR build ----------------
__global__ void k_deg(const int* __restrict__ dst, int* __restrict__ deg){
  int e = blockIdx.x*blockDim.x + threadIdx.x;
  if(e < E_) atomicAdd(&deg[dst[e]], 1);
}
__global__ void k_gcnt(const int* __restrict__ gid, int* __restrict__ gcnt){
  int n = blockIdx.x*blockDim.x + threadIdx.x;
  if(n < N_) atomicAdd(&gcnt[gid[n]], 1);
}
__global__ void __launch_bounds__(1024) k_scanA(const int* __restrict__ deg,
                       int* __restrict__ incl, int* __restrict__ bsum){
  __shared__ int sh[1024];
  int g = blockIdx.x*1024 + threadIdx.x;
  int v = (g < N_) ? deg[g] : 0;
  sh[threadIdx.x]=v; __syncthreads();
  for(int o=1;o<1024;o<<=1){
    int a = (threadIdx.x>=o) ? sh[threadIdx.x-o] : 0;
    __syncthreads();
    sh[threadIdx.x]+=a;
    __syncthreads();
  }
  if(g < N_) incl[g]=sh[threadIdx.x];
  if(threadIdx.x==1023) bsum[blockIdx.x]=sh[1023];
}
__global__ void k_scanB(const int* __restrict__ bsum, int* __restrict__ boff){
  __shared__ int sh[256];
  int t=threadIdx.x;
  int v=(t<196)?bsum[t]:0;
  sh[t]=v; __syncthreads();
  for(int o=1;o<256;o<<=1){
    int a=(t>=o)?sh[t-o]:0; __syncthreads(); sh[t]+=a; __syncthreads();
  }
  if(t<196) boff[t]=sh[t]-v;   // exclusive
}
__global__ void __launch_bounds__(1024) k_scanC(const int* __restrict__ deg,
                       const int* __restrict__ boff, int* __restrict__ noff,
                       int* __restrict__ incl_cursor){
  int g = blockIdx.x*1024 + threadIdx.x;
  if(g >= N_) return;
  int ex = incl_cursor[g] - deg[g] + boff[g>>10];
  noff[g]=ex; incl_cursor[g]=ex;   // cursor = exclusive offset
}
__global__ void k_goff(const int* __restrict__ gcnt, int* __restrict__ goff){
  __shared__ int sh[512];
  int t=threadIdx.x;
  int v=gcnt[t]; sh[t]=v; __syncthreads();
  for(int o=1;o<512;o<<=1){
    int a=(t>=o)?sh[t-o]:0; __syncthreads(); sh[t]+=a; __syncthreads();
  }
  goff[t+1]=sh[t];
  if(t==0) goff[0]=0;
}
// range-partitioned scatter: pass p handles dst in [p*12500,(p+1)*12500) so the
// active csr slice (~800 KB) stays L2-resident -> dense line fills, no write amp
__global__ void k_scatter(const int* __restrict__ src, const int* __restrict__ dst,
                          int* __restrict__ cursor, int* __restrict__ csr){
  int bp = blockIdx.x / 12500, bx = blockIdx.x % 12500;
  int e = bx*256 + threadIdx.x;
  int d = dst[e];
  if(d/12500 != bp) return;
  int p = atomicAdd(&cursor[d], 1);
  csr[p] = src[e];
}

// ---- fused step: gather-sum (fp16 mirror) -> Wm+relu -> GRU (fp32 in-place) ----
__global__ void k_step(const float* __restrict__ Wall, const int* __restrict__ noff,
                       const int* __restrict__ deg, const int* __restrict__ csr,
                       float* __restrict__ out,
                       const __half* __restrict__ curh, __half* __restrict__ nxth){
  int t = blockIdx.x*blockDim.x + threadIdx.x;
  int n = t>>5, lane = t&31;
  if(n >= N_) return;
  int s0 = noff[n], len = deg[n];
  float acc = 0.f;
  int i = 0;
  for(; i+8<=len; i+=8){
    int i0=csr[s0+i+0], i1=csr[s0+i+1], i2=csr[s0+i+2], i3=csr[s0+i+3];
    int i4=csr[s0+i+4], i5=csr[s0+i+5], i6=csr[s0+i+6], i7=csr[s0+i+7];
    float v0=__half2float(curh[(size_t)i0*DD+lane]);
    float v1=__half2float(curh[(size_t)i1*DD+lane]);
    float v2=__half2float(curh[(size_t)i2*DD+lane]);
    float v3=__half2float(curh[(size_t)i3*DD+lane]);
    float v4=__half2float(curh[(size_t)i4*DD+lane]);
    float v5=__half2float(curh[(size_t)i5*DD+lane]);
    float v6=__half2float(curh[(size_t)i6*DD+lane]);
    float v7=__half2float(curh[(size_t)i7*DD+lane]);
    acc += ((v0+v1)+(v2+v3)) + ((v4+v5)+(v6+v7));
  }
  for(; i<len; i++)
    acc += __half2float(curh[(size_t)csr[s0+i]*DD + lane]);
  const float* WmT = Wall + OFF_WMT;
  float m = 0.f;
  #pragma unroll
  for(int k=0;k<DD;k++)
    m = __fmaf_rn(WmT[k*DD+lane], __shfl(acc,k,32), m);
  m = fmaxf(m, 0.f);
  float h = out[(size_t)n*DD + lane];
  const float* WihT = Wall + OFF_WIHGT;
  const float* WhhT = Wall + OFF_WHHGT;
  float a_r  = Wall[OFF_BIHG+lane]      + Wall[OFF_BHHG+lane];
  float a_z  = Wall[OFF_BIHG+DD+lane]   + Wall[OFF_BHHG+DD+lane];
  float a_ni = Wall[OFF_BIHG+2*DD+lane];
  float a_nh = Wall[OFF_BHHG+2*DD+lane];
  #pragma unroll 4
  for(int k=0;k<DD;k++){
    float mk = __shfl(m,k,32), hk = __shfl(h,k,32);
    const float* wi = WihT + k*96;
    const float* wh = WhhT + k*96;
    a_r  = __fmaf_rn(wi[lane],      mk, a_r);
    a_r  = __fmaf_rn(wh[lane],      hk, a_r);
    a_z  = __fmaf_rn(wi[DD+lane],   mk, a_z);
    a_z  = __fmaf_rn(wh[DD+lane],   hk, a_z);
    a_ni = __fmaf_rn(wi[2*DD+lane], mk, a_ni);
    a_nh = __fmaf_rn(wh[2*DD+lane], hk, a_nh);
  }
  float r = sigm(a_r), z = sigm(a_z);
  float nn = tanhfast(a_ni + r*a_nh);
  float ho = (1.f-z)*nn + z*h;
  out[(size_t)n*DD+lane] = ho;
  nxth[(size_t)n*DD+lane] = __float2half(ho);
}

// ---- single-launch Set2Set + readout: block g owns graph g (gid sorted) ----------
#define MAXEV 1024
__global__ void __launch_bounds__(256) k_s2s(const float* __restrict__ Wall,
                       const float* __restrict__ out, const int* __restrict__ goff,
                       void* __restrict__ op, const int* __restrict__ flag){
  int g = blockIdx.x, t = threadIdx.x;
  int lane = t & 31, hw = t >> 5;
  __shared__ float evb[MAXEV];
  __shared__ float red[256];
  __shared__ float qs[64];
  __shared__ float xb[64];
  __shared__ float hb[3][32];
  __shared__ float gbuf[128];
  __shared__ float yb[32];
  int s0 = goff[g], s1 = goff[g+1];
  int len = s1 - s0;
  int lc = len < MAXEV ? len : MAXEV;
  if(t < 64) qs[t] = 0.f;
  if(t < 96) hb[t>>5][t&31] = 0.f;
  float c0=0.f, c1=0.f, c2v=0.f;           // cell states on threads 0..31
  __syncthreads();
  for(int it=0; it<6; it++){
    if(t<64) xb[t]=qs[t];
    __syncthreads();
    // ---- LSTM layer 0 (xdim 64) ----
    if(t<128){
      const float* WT = Wall + OFF_WIH0T; const float* UT = Wall + OFF_WHH0T;
      float gv = Wall[OFF_BIH0+t] + Wall[OFF_BHH0+t];
      #pragma unroll 8
      for(int k=0;k<64;k++) gv = __fmaf_rn(WT[k*128+t], xb[k], gv);
      #pragma unroll 8
      for(int k=0;k<32;k++) gv = __fmaf_rn(UT[k*128+t], hb[0][k], gv);
      gbuf[t]=gv;
    }
    __syncthreads();
    if(t<32){
      float iv=sigm(gbuf[t]), fv=sigm(gbuf[32+t]), gg=tanhfast(gbuf[64+t]), ov=sigm(gbuf[96+t]);
      float c = fv*c0 + iv*gg; c0=c;
      float h2 = ov*tanhfast(c);
      hb[0][t]=h2; xb[t]=h2;
    }
    __syncthreads();
    // ---- LSTM layers 1,2 (xdim 32) ----
    for(int l=1;l<3;l++){
      if(t<128){
        const float* WT = Wall + (l==1?OFF_WIH1T:OFF_WIH2T);
        const float* UT = Wall + (l==1?OFF_WHH1T:OFF_WHH2T);
        int bo=(l-1)*128;
        float gv = Wall[OFF_BIH12+bo+t] + Wall[OFF_BHH12+bo+t];
        #pragma unroll 8
        for(int k=0;k<32;k++) gv = __fmaf_rn(WT[k*128+t], xb[k], gv);
        #pragma unroll 8
        for(int k=0;k<32;k++) gv = __fmaf_rn(UT[k*128+t], hb[l][k], gv);
        gbuf[t]=gv;
      }
      __syncthreads();
      if(t<32){
        float cp = (l==1)?c1:c2v;
        float iv=sigm(gbuf[t]), fv=sigm(gbuf[32+t]), gg=tanhfast(gbuf[64+t]), ov=sigm(gbuf[96+t]);
        float c = fv*cp + iv*gg;
        if(l==1) c1=c; else c2v=c;
        float h2 = ov*tanhfast(c);
        hb[l][t]=h2; xb[t]=h2;
      }
      __syncthreads();
    }
    float q = xb[lane];                      // layer-2 h, per-lane
    // ---- attention pass 1: logits ----
    float lmax = -INFINITY;
    for(int i=hw; i<len; i+=8){
      float v = out[(size_t)(s0+i)*DD+lane]*q;
      #pragma unroll
      for(int o=16;o>0;o>>=1) v += __shfl_xor(v,o,32);
      if(i<lc && lane==0) evb[i]=v;
      lmax = fmaxf(lmax, v);
    }
    red[t]=lmax; __syncthreads();
    for(int o=128;o>0;o>>=1){ if(t<o) red[t]=fmaxf(red[t],red[t+o]); __syncthreads(); }
    float mx=red[0]; __syncthreads();
    // ---- pass 2: sum of exp ----
    float sm=0.f;
    for(int i=t;i<len;i+=256){
      float v;
      if(i<lc) v=evb[i];
      else { v=0.f; for(int k=0;k<DD;k++) v += out[(size_t)(s0+i)*DD+k]*xb[k]; }
      sm += __expf(v-mx);
    }
    red[t]=sm; __syncthreads();
    for(int o=128;o>0;o>>=1){ if(t<o) red[t]+=red[t+o]; __syncthreads(); }
    sm=red[0]; __syncthreads();
    float inv = (sm>0.f) ? 1.f/sm : 0.f;
    // ---- pass 3: weighted sum ----
    float acc=0.f;
    for(int i=hw;i<len;i+=8){
      float fv = out[(size_t)(s0+i)*DD+lane];
      float v;
      if(i<lc) v=evb[i];
      else { float vv=fv*q; 
             #pragma unroll
             for(int o=16;o>0;o>>=1) vv += __shfl_xor(vv,o,32);
             v=vv; }
      acc = __fmaf_rn(__expf(v-mx), fv, acc);
    }
    red[hw*32+lane]=acc; __syncthreads();
    if(t<32){
      float s=0.f;
      #pragma unroll
      for(int k=0;k<8;k++) s+=red[k*32+t];
      qs[32+t]=s*inv; qs[t]=xb[t];
    }
    __syncthreads();
  }
  // ---- readout MLP ----
  if(t<32){
    const float* W1 = Wall+OFF_WR1T;
    float s = Wall[OFF_BR1+t];
    #pragma unroll 8
    for(int k=0;k<64;k++) s = __fmaf_rn(W1[k*32+t], qs[k], s);
    yb[t]=fmaxf(s,0.f);
  }
  __syncthreads();
  if(t<32){
    const float* W2 = Wall+OFF_WR2T;
    float o = Wall[OFF_BR2+t];
    #pragma unroll 8
    for(int k=0;k<32;k++) o = __fmaf_rn(W2[k*32+t], yb[k], o);
    if(flag[0]) ((__hip_bfloat16*)op)[g*32+t]=__float2bfloat16(o);
    else        ((float*)op)[g*32+t]=o;
  }
}

extern "C" void kernel_launch(void* const* d_in, const int* in_sizes, int n_in,
                              void* d_out, int out_size, void* d_ws, size_t ws_size,
                              hipStream_t stream) {
  const int* nt  = (const int*)d_in[0];
  const int* src = (const int*)d_in[1];
  const int* dst = (const int*)d_in[2];
  const int* gid = (const int*)d_in[3];
  float* W = (float*)d_ws;
  char* base = (char*)d_ws;
  __half* h0 = (__half*)(base + H0_BYTE);
  __half* h1 = (__half*)(base + H1_BYTE);
  int* I = (int*)(base + INT_BASE);
  float* out = W+OFF_OUT;
  int* deg=I+I_DEG; int* gcnt=I+I_GCNT; int* noff=I+I_NOFF; int* cursor=I+I_CURSOR;
  int* goff=I+I_GOFF; int* bsum=I+I_BSUM; int* boff=I+I_BOFF; int* csr=I+I_CSR;
  int* flag=I+I_FLAG;

  hipMemsetAsync(deg, 0, (size_t)(N_+B_)*4, stream);   // deg + gcnt adjacent

  k_detect<<<1,64,0,stream>>>((const unsigned int*)d_in[4], flag);

  PrepArgs pa;
  const int sidx[22]={4,6,10,11,14,15,18,19,21,23, 5,7,8,9,12,13,16,16,17,17,20,22};
  const int offs[22]={OFF_EMB,OFF_B0,OFF_BIHG,OFF_BHHG,OFF_BIH0,OFF_BHH0,OFF_BIH12,
                      OFF_BHH12,OFF_BR1,OFF_BR2, OFF_W0T,OFF_WMT,OFF_WIHGT,OFF_WHHGT,
                      OFF_WIH0T,OFF_WHH0T,OFF_WIH1T,OFF_WIH2T,OFF_WHH1T,OFF_WHH2T,
                      OFF_WR1T,OFF_WR2T};
  const int szs[22]={3232,32,96,96,128,128,256,256,32,32, 1024,1024,3072,3072,
                     8192,4096,4096,4096,4096,4096,2048,1024};
  const int trR[22]={0,0,0,0,0,0,0,0,0,0, 32,32,96,96,128,128,128,128,128,128,32,32};
  const int sof[22]={0,0,0,0,0,0,0,0,0,0, 0,0,0,0,0,0,0,4096,0,4096,0,0};
  for(int i=0;i<22;i++){ pa.s[i]=d_in[sidx[i]]; pa.off[i]=offs[i]; pa.sz[i]=szs[i];
                         pa.trR[i]=trR[i]; pa.soff[i]=sof[i]; }
  hipLaunchKernelGGL(k_prep, dim3(32,22), dim3(256), 0, stream, pa, W, flag);

  k_lin0<<<782,256,0,stream>>>(nt, W, out, h0);
  k_deg<<<12500,256,0,stream>>>(dst, deg);
  k_gcnt<<<782,256,0,stream>>>(gid, gcnt);
  k_scanA<<<196,1024,0,stream>>>(deg, cursor, bsum);
  k_scanB<<<1,256,0,stream>>>(bsum, boff);
  k_scanC<<<196,1024,0,stream>>>(deg, boff, noff, cursor);
  k_goff<<<1,512,0,stream>>>(gcnt, goff);
  k_scatter<<<12500*16,256,0,stream>>>(src, dst, cursor, csr);

  // 6 MP steps: fp32 `out` in place; fp16 gather mirror double-buffered
  __half* curh = h0; __half* nxth = h1;
  for(int s=0;s<6;s++){
    k_step<<<25000,256,0,stream>>>(W, noff, deg, csr, out, curh, nxth);
    __half* tmp = curh; curh = nxth; nxth = tmp;
  }
  // whole Set2Set + readout in one launch (block g == graph g, fully independent)
  k_s2s<<<B_,256,0,stream>>>(W, out, goff, d_out, flag);
}

// Round 7
// 1805.745 us; speedup vs baseline: 1.4954x; 1.1073x over previous
//
#include <hip/hip_runtime.h>
#include <hip/hip_bf16.h>
#include <hip/hip_fp16.h>

#define DD 32
constexpr int N_ = 200000;
constexpr int E_ = 3200000;
constexpr int B_ = 512;

// ---------------- workspace layout ----------------
constexpr int OFF_EMB=0, OFF_B0=3232, OFF_BIHG=3264, OFF_BHHG=3360, OFF_BIH0=3456,
  OFF_BHH0=3584, OFF_BIH12=3712, OFF_BHH12=3968, OFF_BR1=4224, OFF_BR2=4256,
  OFF_W0T=4288, OFF_WMT=5312, OFF_WIHGT=6336, OFF_WHHGT=9408,
  OFF_WIH0T=12480, OFF_WHH0T=20672, OFF_WIH1T=24768, OFF_WHH1T=28864,
  OFF_WIH2T=32960, OFF_WHH2T=37056, OFF_WR1T=41152, OFF_WR2T=43200;
constexpr long FLOAT_END=44288L;
constexpr size_t H0_BYTE = (size_t)FLOAT_END*4;            // fp16 state A, N*32*2 B
constexpr size_t H1_BYTE = H0_BYTE + (size_t)N_*DD*2;      // fp16 state B
constexpr size_t INT_BASE = H1_BYTE + (size_t)N_*DD*2;     // 25777152, 256B aligned
// int offsets (in ints, from INT_BASE)
constexpr int I_DEG=0, I_NOFF=200512, I_CURSOR=400512, I_GOFF=600512,
  I_BSUM=601088, I_BOFF=601344, I_CSR=601600;      // csr: E ints
constexpr int I_FLAG=3801600;

__device__ __forceinline__ float bf2f(unsigned short u){ return __uint_as_float(((unsigned)u)<<16); }
__device__ __forceinline__ float sigm(float x){ return 1.0f/(1.0f+__expf(-x)); }
__device__ __forceinline__ float tanhfast(float x){ return 1.0f - 2.0f/(__expf(2.0f*x)+1.0f); }

// ---------------- input-dtype detection ----------------
__global__ void k_detect(const unsigned int* __restrict__ emb_raw, int* __restrict__ flag){
  if(threadIdx.x==0){
    unsigned v=0;
    for(int i=16;i<32;i++) v |= emb_raw[i];
    flag[0] = v ? 1 : 0;   // 1 = bf16 inputs, 0 = f32 inputs
  }
}

// -------- weight prep: (bf16|f32) -> fp32; trR!=0: transpose [R x C] -> [C x R] -----
struct PrepArgs { const void* s[22]; int off[22]; int sz[22]; int trR[22]; int soff[22]; };

__global__ void k_prep(PrepArgs a, float* __restrict__ W, const int* __restrict__ flag){
  int bf = flag[0];
  int seg = blockIdx.y;
  int i = blockIdx.x*256 + threadIdx.x;
  if(i >= a.sz[seg]) return;
  int R = a.trR[seg];
  int sidx;
  if(R){ int C = a.sz[seg]/R; sidx = (i%R)*C + (i/R); } else sidx = i;
  sidx += a.soff[seg];
  float v = bf ? bf2f(((const unsigned short*)a.s[seg])[sidx])
               : ((const float*)a.s[seg])[sidx];
  W[a.off[seg]+i] = v;
}

// ---------------- lin0: h0[n] = fp16(relu(W0 @ emb[node_type[n]] + b0)) -----------
__global__ void k_lin0(const int* __restrict__ nt, const float* __restrict__ Wall,
                       __half* __restrict__ hmir){
  int n = blockIdx.x*blockDim.x + threadIdx.x;
  if(n >= N_) return;
  const float* er  = Wall + OFF_EMB + nt[n]*DD;
  const float* W0T = Wall + OFF_W0T;
  const float* b0  = Wall + OFF_B0;
  float m[DD];
  #pragma unroll
  for(int j=0;j<DD;j++) m[j]=b0[j];
  #pragma unroll 4
  for(int k=0;k<DD;k++){
    float xk = er[k];
    #pragma unroll
    for(int j=0;j<DD;j++) m[j] = __fmaf_rn(W0T[k*DD+j], xk, m[j]);
  }
  __half* hrow = hmir + (size_t)n*DD;
  #pragma unroll
  for(int j=0;j<DD;j++) hrow[j]=__float2half(fmaxf(m[j],0.f));
}

// ---------------- CSR build ----------------
__global__ void k_deg(const int* __restrict__ dst, int* __restrict__ deg){
  int e = blockIdx.x*blockDim.x + threadIdx.x;
  if(e < E_) atomicAdd(&deg[dst[e]], 1);
}
__global__ void __launch_bounds__(1024) k_scanA(const int* __restrict__ deg,
                       int* __restrict__ incl, int* __restrict__ bsum){
  __shared__ int sh[1024];
  int g = blockIdx.x*1024 + threadIdx.x;
  int v = (g < N_) ? deg[g] : 0;
  sh[threadIdx.x]=v; __syncthreads();
  for(int o=1;o<1024;o<<=1){
    int a = (threadIdx.x>=o) ? sh[threadIdx.x-o] : 0;
    __syncthreads();
    sh[threadIdx.x]+=a;
    __syncthreads();
  }
  if(g < N_) incl[g]=sh[threadIdx.x];
  if(threadIdx.x==1023) bsum[blockIdx.x]=sh[1023];
}
__global__ void k_scanB(const int* __restrict__ bsum, int* __restrict__ boff){
  __shared__ int sh[256];
  int t=threadIdx.x;
  int v=(t<196)?bsum[t]:0;
  sh[t]=v; __syncthreads();
  for(int o=1;o<256;o<<=1){
    int a=(t>=o)?sh[t-o]:0; __syncthreads(); sh[t]+=a; __syncthreads();
  }
  if(t<196) boff[t]=sh[t]-v;   // exclusive
}
__global__ void __launch_bounds__(1024) k_scanC(const int* __restrict__ deg,
                       const int* __restrict__ boff, int* __restrict__ noff,
                       int* __restrict__ incl_cursor){
  int g = blockIdx.x*1024 + threadIdx.x;
  if(g >= N_) return;
  int ex = incl_cursor[g] - deg[g] + boff[g>>10];
  noff[g]=ex; incl_cursor[g]=ex;   // cursor = exclusive offset
}
// goff[g] = lower_bound(gid, g)  (gid sorted)
__global__ void k_goff(const int* __restrict__ gid, int* __restrict__ goff){
  int g = blockIdx.x*256 + threadIdx.x;
  if(g > B_) return;
  int lo=0, hi=N_;
  while(lo<hi){ int mid=(lo+hi)>>1; if(gid[mid]<g) lo=mid+1; else hi=mid; }
  goff[g]=lo;
}
// range-partitioned scatter: pass p handles dst in [p*12500,(p+1)*12500) so the
// active csr slice (~800 KB) stays L2-resident -> dense line fills, no write amp
__global__ void k_scatter(const int* __restrict__ src, const int* __restrict__ dst,
                          int* __restrict__ cursor, int* __restrict__ csr){
  int bp = blockIdx.x / 12500, bx = blockIdx.x % 12500;
  int e = bx*256 + threadIdx.x;
  int d = dst[e];
  if(d/12500 != bp) return;
  int p = atomicAdd(&cursor[d], 1);
  csr[p] = src[e];
}

// ---- fused step: gather-sum (fp16) -> Wm+relu -> GRU -> nxth (fp16 state only) ----
__global__ void k_step(const float* __restrict__ Wall, const int* __restrict__ noff,
                       const int* __restrict__ deg, const int* __restrict__ csr,
                       const __half* __restrict__ curh, __half* __restrict__ nxth){
  int t = blockIdx.x*blockDim.x + threadIdx.x;
  int n = t>>5, lane = t&31;
  if(n >= N_) return;
  int s0 = noff[n], len = deg[n];
  float acc = 0.f;
  int i = 0;
  for(; i+8<=len; i+=8){
    int i0=csr[s0+i+0], i1=csr[s0+i+1], i2=csr[s0+i+2], i3=csr[s0+i+3];
    int i4=csr[s0+i+4], i5=csr[s0+i+5], i6=csr[s0+i+6], i7=csr[s0+i+7];
    float v0=__half2float(curh[(size_t)i0*DD+lane]);
    float v1=__half2float(curh[(size_t)i1*DD+lane]);
    float v2=__half2float(curh[(size_t)i2*DD+lane]);
    float v3=__half2float(curh[(size_t)i3*DD+lane]);
    float v4=__half2float(curh[(size_t)i4*DD+lane]);
    float v5=__half2float(curh[(size_t)i5*DD+lane]);
    float v6=__half2float(curh[(size_t)i6*DD+lane]);
    float v7=__half2float(curh[(size_t)i7*DD+lane]);
    acc += ((v0+v1)+(v2+v3)) + ((v4+v5)+(v6+v7));
  }
  for(; i<len; i++)
    acc += __half2float(curh[(size_t)csr[s0+i]*DD + lane]);
  const float* WmT = Wall + OFF_WMT;
  float m = 0.f;
  #pragma unroll
  for(int k=0;k<DD;k++)
    m = __fmaf_rn(WmT[k*DD+lane], __shfl(acc,k,32), m);
  m = fmaxf(m, 0.f);
  float h = __half2float(curh[(size_t)n*DD + lane]);
  const float* WihT = Wall + OFF_WIHGT;
  const float* WhhT = Wall + OFF_WHHGT;
  float a_r  = Wall[OFF_BIHG+lane]      + Wall[OFF_BHHG+lane];
  float a_z  = Wall[OFF_BIHG+DD+lane]   + Wall[OFF_BHHG+DD+lane];
  float a_ni = Wall[OFF_BIHG+2*DD+lane];
  float a_nh = Wall[OFF_BHHG+2*DD+lane];
  #pragma unroll 4
  for(int k=0;k<DD;k++){
    float mk = __shfl(m,k,32), hk = __shfl(h,k,32);
    const float* wi = WihT + k*96;
    const float* wh = WhhT + k*96;
    a_r  = __fmaf_rn(wi[lane],      mk, a_r);
    a_r  = __fmaf_rn(wh[lane],      hk, a_r);
    a_z  = __fmaf_rn(wi[DD+lane],   mk, a_z);
    a_z  = __fmaf_rn(wh[DD+lane],   hk, a_z);
    a_ni = __fmaf_rn(wi[2*DD+lane], mk, a_ni);
    a_nh = __fmaf_rn(wh[2*DD+lane], hk, a_nh);
  }
  float r = sigm(a_r), z = sigm(a_z);
  float nn = tanhfast(a_ni + r*a_nh);
  float ho = (1.f-z)*nn + z*h;
  nxth[(size_t)n*DD+lane] = __float2half(ho);
}

// ---- single-launch Set2Set + readout: block g owns graph g (gid sorted) ----------
#define MAXEV 1024
__global__ void __launch_bounds__(256) k_s2s(const float* __restrict__ Wall,
                       const __half* __restrict__ hstate, const int* __restrict__ goff,
                       void* __restrict__ op, const int* __restrict__ flag){
  int g = blockIdx.x, t = threadIdx.x;
  int lane = t & 31, hw = t >> 5;
  __shared__ float evb[MAXEV];
  __shared__ float red[256];
  __shared__ float qs[64];
  __shared__ float xb[64];
  __shared__ float hb[3][32];
  __shared__ float gbuf[128];
  __shared__ float yb[32];
  int s0 = goff[g], s1 = goff[g+1];
  int len = s1 - s0;
  int lc = len < MAXEV ? len : MAXEV;
  if(t < 64) qs[t] = 0.f;
  if(t < 96) hb[t>>5][t&31] = 0.f;
  float c0=0.f, c1=0.f, c2v=0.f;           // cell states on threads 0..31
  __syncthreads();
  for(int it=0; it<6; it++){
    if(t<64) xb[t]=qs[t];
    __syncthreads();
    // ---- LSTM layer 0 (xdim 64) ----
    if(t<128){
      const float* WT = Wall + OFF_WIH0T; const float* UT = Wall + OFF_WHH0T;
      float gv = Wall[OFF_BIH0+t] + Wall[OFF_BHH0+t];
      #pragma unroll 8
      for(int k=0;k<64;k++) gv = __fmaf_rn(WT[k*128+t], xb[k], gv);
      #pragma unroll 8
      for(int k=0;k<32;k++) gv = __fmaf_rn(UT[k*128+t], hb[0][k], gv);
      gbuf[t]=gv;
    }
    __syncthreads();
    if(t<32){
      float iv=sigm(gbuf[t]), fv=sigm(gbuf[32+t]), gg=tanhfast(gbuf[64+t]), ov=sigm(gbuf[96+t]);
      float c = fv*c0 + iv*gg; c0=c;
      float h2 = ov*tanhfast(c);
      hb[0][t]=h2; xb[t]=h2;
    }
    __syncthreads();
    // ---- LSTM layers 1,2 (xdim 32) ----
    for(int l=1;l<3;l++){
      if(t<128){
        const float* WT = Wall + (l==1?OFF_WIH1T:OFF_WIH2T);
        const float* UT = Wall + (l==1?OFF_WHH1T:OFF_WHH2T);
        int bo=(l-1)*128;
        float gv = Wall[OFF_BIH12+bo+t] + Wall[OFF_BHH12+bo+t];
        #pragma unroll 8
        for(int k=0;k<32;k++) gv = __fmaf_rn(WT[k*128+t], xb[k], gv);
        #pragma unroll 8
        for(int k=0;k<32;k++) gv = __fmaf_rn(UT[k*128+t], hb[l][k], gv);
        gbuf[t]=gv;
      }
      __syncthreads();
      if(t<32){
        float cp = (l==1)?c1:c2v;
        float iv=sigm(gbuf[t]), fv=sigm(gbuf[32+t]), gg=tanhfast(gbuf[64+t]), ov=sigm(gbuf[96+t]);
        float c = fv*cp + iv*gg;
        if(l==1) c1=c; else c2v=c;
        float h2 = ov*tanhfast(c);
        hb[l][t]=h2; xb[t]=h2;
      }
      __syncthreads();
    }
    float q = xb[lane];                      // layer-2 h, per-lane
    // ---- attention pass 1: logits ----
    float lmax = -INFINITY;
    for(int i=hw; i<len; i+=8){
      float v = __half2float(hstate[(size_t)(s0+i)*DD+lane])*q;
      #pragma unroll
      for(int o=16;o>0;o>>=1) v += __shfl_xor(v,o,32);
      if(i<lc && lane==0) evb[i]=v;
      lmax = fmaxf(lmax, v);
    }
    red[t]=lmax; __syncthreads();
    for(int o=128;o>0;o>>=1){ if(t<o) red[t]=fmaxf(red[t],red[t+o]); __syncthreads(); }
    float mx=red[0]; __syncthreads();
    // ---- pass 2: sum of exp ----
    float sm=0.f;
    for(int i=t;i<len;i+=256){
      float v;
      if(i<lc) v=evb[i];
      else { v=0.f; for(int k=0;k<DD;k++) v += __half2float(hstate[(size_t)(s0+i)*DD+k])*xb[k]; }
      sm += __expf(v-mx);
    }
    red[t]=sm; __syncthreads();
    for(int o=128;o>0;o>>=1){ if(t<o) red[t]+=red[t+o]; __syncthreads(); }
    sm=red[0]; __syncthreads();
    float inv = (sm>0.f) ? 1.f/sm : 0.f;
    // ---- pass 3: weighted sum ----
    float acc=0.f;
    for(int i=hw;i<len;i+=8){
      float fv = __half2float(hstate[(size_t)(s0+i)*DD+lane]);
      float v;
      if(i<lc) v=evb[i];
      else { float vv=fv*q;
             #pragma unroll
             for(int o=16;o>0;o>>=1) vv += __shfl_xor(vv,o,32);
             v=vv; }
      acc = __fmaf_rn(__expf(v-mx), fv, acc);
    }
    red[hw*32+lane]=acc; __syncthreads();
    if(t<32){
      float s=0.f;
      #pragma unroll
      for(int k=0;k<8;k++) s+=red[k*32+t];
      qs[32+t]=s*inv; qs[t]=xb[t];
    }
    __syncthreads();
  }
  // ---- readout MLP ----
  if(t<32){
    const float* W1 = Wall+OFF_WR1T;
    float s = Wall[OFF_BR1+t];
    #pragma unroll 8
    for(int k=0;k<64;k++) s = __fmaf_rn(W1[k*32+t], qs[k], s);
    yb[t]=fmaxf(s,0.f);
  }
  __syncthreads();
  if(t<32){
    const float* W2 = Wall+OFF_WR2T;
    float o = Wall[OFF_BR2+t];
    #pragma unroll 8
    for(int k=0;k<32;k++) o = __fmaf_rn(W2[k*32+t], yb[k], o);
    if(flag[0]) ((__hip_bfloat16*)op)[g*32+t]=__float2bfloat16(o);
    else        ((float*)op)[g*32+t]=o;
  }
}

extern "C" void kernel_launch(void* const* d_in, const int* in_sizes, int n_in,
                              void* d_out, int out_size, void* d_ws, size_t ws_size,
                              hipStream_t stream) {
  const int* nt  = (const int*)d_in[0];
  const int* src = (const int*)d_in[1];
  const int* dst = (const int*)d_in[2];
  const int* gid = (const int*)d_in[3];
  float* W = (float*)d_ws;
  char* base = (char*)d_ws;
  __half* h0 = (__half*)(base + H0_BYTE);
  __half* h1 = (__half*)(base + H1_BYTE);
  int* I = (int*)(base + INT_BASE);
  int* deg=I+I_DEG; int* noff=I+I_NOFF; int* cursor=I+I_CURSOR;
  int* goff=I+I_GOFF; int* bsum=I+I_BSUM; int* boff=I+I_BOFF; int* csr=I+I_CSR;
  int* flag=I+I_FLAG;

  hipMemsetAsync(deg, 0, (size_t)N_*4, stream);

  k_detect<<<1,64,0,stream>>>((const unsigned int*)d_in[4], flag);

  PrepArgs pa;
  const int sidx[22]={4,6,10,11,14,15,18,19,21,23, 5,7,8,9,12,13,16,16,17,17,20,22};
  const int offs[22]={OFF_EMB,OFF_B0,OFF_BIHG,OFF_BHHG,OFF_BIH0,OFF_BHH0,OFF_BIH12,
                      OFF_BHH12,OFF_BR1,OFF_BR2, OFF_W0T,OFF_WMT,OFF_WIHGT,OFF_WHHGT,
                      OFF_WIH0T,OFF_WHH0T,OFF_WIH1T,OFF_WIH2T,OFF_WHH1T,OFF_WHH2T,
                      OFF_WR1T,OFF_WR2T};
  const int szs[22]={3232,32,96,96,128,128,256,256,32,32, 1024,1024,3072,3072,
                     8192,4096,4096,4096,4096,4096,2048,1024};
  const int trR[22]={0,0,0,0,0,0,0,0,0,0, 32,32,96,96,128,128,128,128,128,128,32,32};
  const int sof[22]={0,0,0,0,0,0,0,0,0,0, 0,0,0,0,0,0,0,4096,0,4096,0,0};
  for(int i=0;i<22;i++){ pa.s[i]=d_in[sidx[i]]; pa.off[i]=offs[i]; pa.sz[i]=szs[i];
                         pa.trR[i]=trR[i]; pa.soff[i]=sof[i]; }
  hipLaunchKernelGGL(k_prep, dim3(32,22), dim3(256), 0, stream, pa, W, flag);

  k_lin0<<<782,256,0,stream>>>(nt, W, h0);
  k_deg<<<12500,256,0,stream>>>(dst, deg);
  k_scanA<<<196,1024,0,stream>>>(deg, cursor, bsum);
  k_scanB<<<1,256,0,stream>>>(bsum, boff);
  k_scanC<<<196,1024,0,stream>>>(deg, boff, noff, cursor);
  k_goff<<<3,256,0,stream>>>(gid, goff);
  k_scatter<<<12500*16,256,0,stream>>>(src, dst, cursor, csr);

  // 6 MP steps on fp16 double-buffered state (even count -> final state in h0)
  __half* curh = h0; __half* nxth = h1;
  for(int s=0;s<6;s++){
    k_step<<<25000,256,0,stream>>>(W, noff, deg, csr, curh, nxth);
    __half* tmp = curh; curh = nxth; nxth = tmp;
  }
  // whole Set2Set + readout in one launch (block g == graph g, fully independent)
  k_s2s<<<B_,256,0,stream>>>(W, curh, goff, d_out, flag);
}